// Round 16
// baseline (647.478 us; speedup 1.0000x reference)
//
#include <hip/hip_runtime.h>
#include <hip/hip_bf16.h>

// Problem constants
#define BB 8
#define CC 512
#define LLOC 2304        // 48*48
#define NHEADS 8
#define DH 64
#define BH 64            // BB*NHEADS
#define TKSEL 288        // 2304/8

typedef unsigned int u32;
typedef short short8 __attribute__((ext_vector_type(8)));
typedef float f32x4 __attribute__((ext_vector_type(4)));
typedef float f32x2 __attribute__((ext_vector_type(2)));

__device__ inline unsigned short f2bf(float f) {
  unsigned u = __float_as_uint(f);
  u += 0x7FFFu + ((u >> 16) & 1u);
  return (unsigned short)(u >> 16);
}
__device__ inline float b2f(unsigned short h) {
  return __uint_as_float(((unsigned)h) << 16);
}

// global -> LDS direct async copy, 16B/lane; dst = wave-uniform base (+lane*16 implicit)
#define GLOAD_LDS(gsrc, ldst) \
  __builtin_amdgcn_global_load_lds((const __attribute__((address_space(1))) u32*)(gsrc), \
                                   (__attribute__((address_space(3))) u32*)(ldst), 16, 0, 0)

// ---------------------------------------------------------------------------
__device__ inline void tf2x32(unsigned ks0, unsigned ks1, unsigned x0, unsigned x1,
                              unsigned& y0, unsigned& y1) {
  unsigned ks2 = ks0 ^ ks1 ^ 0x1BD11BDAu;
#define TF_R(r) { x0 += x1; x1 = (x1 << (r)) | (x1 >> (32-(r))); x1 ^= x0; }
  x0 += ks0; x1 += ks1;
  TF_R(13) TF_R(15) TF_R(26) TF_R(6)
  x0 += ks1; x1 += ks2 + 1u;
  TF_R(17) TF_R(29) TF_R(16) TF_R(24)
  x0 += ks2; x1 += ks0 + 2u;
  TF_R(13) TF_R(15) TF_R(26) TF_R(6)
  x0 += ks0; x1 += ks1 + 3u;
  TF_R(17) TF_R(29) TF_R(16) TF_R(24)
  x0 += ks1; x1 += ks2 + 4u;
  TF_R(13) TF_R(15) TF_R(26) TF_R(6)
  x0 += ks2; x1 += ks0 + 5u;
#undef TF_R
  y0 = x0; y1 = x1;
}

// JAX randint(key(42), (64,288), 0, 2304), partitionable threefry, XOR-fold
__global__ __launch_bounds__(256) void k_threefry(int* __restrict__ idxRand) {
  unsigned i = blockIdx.x * 256 + threadIdx.x;   // 0..18431
  if (i >= 18432u) return;
  unsigned a0, a1, b0, b1;
  tf2x32(0u, 42u, 0u, 0u, a0, a1);   // k1
  tf2x32(0u, 42u, 0u, 1u, b0, b1);   // k2
  unsigned h0, h1, l0, l1;
  tf2x32(a0, a1, 0u, i, h0, h1);
  tf2x32(b0, b1, 0u, i, l0, l1);
  unsigned h = h0 ^ h1;
  unsigned l = l0 ^ l1;
  const unsigned span = 2304u;
  idxRand[i] = (int)(((h % span) * 256u + (l % span)) % span);
}

// ---------------------------------------------------------------------------
// All three W -> bf16 hi/lo conversions in one launch (range dispatch).
// Concatenated element space: kv [0,524288), q [524288,786432), out [786432,1048576)
__global__ __launch_bounds__(256) void k_prep_w_all(
    const float* __restrict__ w_kv, const float* __restrict__ w_q,
    const float* __restrict__ w_out, const float* __restrict__ g_ctx,
    const float* __restrict__ g_qs,
    unsigned short* __restrict__ Wkv_hi, unsigned short* __restrict__ Wkv_lo,
    unsigned short* __restrict__ Wq_hi,  unsigned short* __restrict__ Wq_lo,
    unsigned short* __restrict__ Wo_hi,  unsigned short* __restrict__ Wo_lo) {
  int i2 = (blockIdx.x * 256 + threadIdx.x) * 2;
  const float* W; const float* G;
  unsigned short *Wh, *Wl; int base;
  if (i2 < 524288) { W = w_kv; G = g_ctx; Wh = Wkv_hi; Wl = Wkv_lo; base = 0; }
  else if (i2 < 786432) { W = w_q; G = g_qs; Wh = Wq_hi; Wl = Wq_lo; base = 524288; }
  else { W = w_out; G = nullptr; Wh = Wo_hi; Wl = Wo_lo; base = 786432; }
  int i = i2 - base;
  int c = i & 511;
  float2 w2 = *(const float2*)&W[i];
  float g0 = G ? G[c] : 1.f, g1 = G ? G[c + 1] : 1.f;
  float f0 = w2.x * g0, f1 = w2.y * g1;
  unsigned short h0 = f2bf(f0), h1 = f2bf(f1);
  unsigned short q0 = f2bf(f0 - b2f(h0)), q1 = f2bf(f1 - b2f(h1));
  *(unsigned*)&Wh[i] = (unsigned)h0 | ((unsigned)h1 << 16);
  *(unsigned*)&Wl[i] = (unsigned)q0 | ((unsigned)q1 << 16);
}

// ---------------------------------------------------------------------------
// FUSED channel-LN stats + normalize + transpose + bf16 hi/lo split:
// X[b][c][loc] -> Xt[b][loc][512]. One block = 64 locs x all 512 c.
// Phase 1: stats (identical summation order to the old k_ln_stats).
// Phase 2: 8 chunks of 64 c through a 64x65 LDS transpose (L3-hot re-read).
__global__ __launch_bounds__(256) void k_prep_xf(const float* __restrict__ X,
    unsigned short* __restrict__ Xh, unsigned short* __restrict__ Xl) {
  int b = blockIdx.y, loc0 = blockIdx.x * 64;
  int t = threadIdx.x, lx = t & 63, cg = t >> 6;
  const float* xb = X + (size_t)b * CC * LLOC;
  float s = 0.f, s2 = 0.f;
  for (int c = cg; c < CC; c += 4) {
    float v = xb[(size_t)c * LLOC + loc0 + lx];
    s += v; s2 += v * v;
  }
  __shared__ float sh[2][256];
  __shared__ float mS[64], rS[64];
  sh[0][t] = s; sh[1][t] = s2;
  __syncthreads();
  if (t < 64) {
    float S  = sh[0][t] + sh[0][t+64] + sh[0][t+128] + sh[0][t+192];
    float S2 = sh[1][t] + sh[1][t+64] + sh[1][t+128] + sh[1][t+192];
    float mean = S * (1.f/512.f);
    float var  = S2 * (1.f/512.f) - mean * mean;
    mS[t] = mean;
    rS[t] = 1.f / sqrtf(var + 1e-5f);
  }
  __syncthreads();
  __shared__ float sm[64][65];
  float mean = mS[lx], rstd = rS[lx];
  int loc = t >> 2, cs = (t & 3) * 16;
  for (int cc = 0; cc < 8; ++cc) {
    int c0 = cc * 64;
#pragma unroll
    for (int i = 0; i < 16; ++i) {
      int c = cg + i * 4;
      float v = xb[(size_t)(c0 + c) * LLOC + loc0 + lx];
      sm[c][lx] = (v - mean) * rstd;
    }
    __syncthreads();
    unsigned uh[8], ul[8];
#pragma unroll
    for (int j = 0; j < 8; ++j) {
      float f0 = sm[cs + j*2][loc];
      float f1 = sm[cs + j*2 + 1][loc];
      unsigned short h0 = f2bf(f0), h1 = f2bf(f1);
      unsigned short q0 = f2bf(f0 - b2f(h0)), q1 = f2bf(f1 - b2f(h1));
      uh[j] = (unsigned)h0 | ((unsigned)h1 << 16);
      ul[j] = (unsigned)q0 | ((unsigned)q1 << 16);
    }
    size_t base = ((size_t)b * LLOC + loc0 + loc) * 512 + c0 + cs;
    *(uint4*)(Xh + base)     = make_uint4(uh[0], uh[1], uh[2], uh[3]);
    *(uint4*)(Xh + base + 8) = make_uint4(uh[4], uh[5], uh[6], uh[7]);
    *(uint4*)(Xl + base)     = make_uint4(ul[0], ul[1], ul[2], ul[3]);
    *(uint4*)(Xl + base + 8) = make_uint4(ul[4], ul[5], ul[6], ul[7]);
    __syncthreads();
  }
}

// ---------------------------------------------------------------------------
// 3-pass split-bf16 MFMA GEMM (~f32 precision) with FUSED L2-NORM epilogue:
// dst = l2norm(W*X^T) over each 64-dim head; K/Q layout out.
// If Qb != nullptr, also emit swizzled bf16 copy (for MFMA attention).
__global__ __launch_bounds__(256) void k_mfma3(
    const unsigned short* __restrict__ Wh, const unsigned short* __restrict__ Wl,
    const unsigned short* __restrict__ Xh, const unsigned short* __restrict__ Xl,
    float* __restrict__ dst, unsigned short* __restrict__ Qb) {
  int b = blockIdx.z;
  int o0 = blockIdx.y * 128, loc0 = blockIdx.x * 128;
  int t = threadIdx.x, l = t & 63, w = t >> 6;
  int wr = w >> 1, wc = w & 1;
  __shared__ unsigned short Ah[128*64], Al[128*64], Bh[128*64], Bl[128*64];
  f32x4 acc[4][4];
#pragma unroll
  for (int i = 0; i < 4; ++i)
#pragma unroll
    for (int j = 0; j < 4; ++j) acc[i][j] = (f32x4){0.f, 0.f, 0.f, 0.f};

  const char* WhC = (const char*)Wh;
  const char* WlC = (const char*)Wl;
  const char* XhC = (const char*)(Xh + (size_t)b * LLOC * 512);
  const char* XlC = (const char*)(Xl + (size_t)b * LLOC * 512);
  int srow = l >> 3;
  int schunk = (l & 7) ^ srow;

  for (int kt = 0; kt < 8; ++kt) {
    int kb = kt * 128;
#pragma unroll
    for (int j = 0; j < 4; ++j) {
      int r = w * 32 + j * 8;
      size_t arow = (size_t)(o0 + r + srow) * 1024 + kb + schunk * 16;
      size_t brow = (size_t)(loc0 + r + srow) * 1024 + kb + schunk * 16;
      GLOAD_LDS(WhC + arow, ((char*)Ah) + r * 128);
      GLOAD_LDS(WlC + arow, ((char*)Al) + r * 128);
      GLOAD_LDS(XhC + brow, ((char*)Bh) + r * 128);
      GLOAD_LDS(XlC + brow, ((char*)Bl) + r * 128);
    }
    __syncthreads();
#pragma unroll
    for (int ks = 0; ks < 2; ++ks) {
      short8 ah[4], al[4], bh[4], bl[4];
#pragma unroll
      for (int ot = 0; ot < 4; ++ot) {
        int row = wr * 64 + ot * 16 + (l & 15);
        int off = row * 128 + ((ks * 4 + (l >> 4)) ^ (row & 7)) * 16;
        ah[ot] = *(const short8*)(((const char*)Ah) + off);
        al[ot] = *(const short8*)(((const char*)Al) + off);
      }
#pragma unroll
      for (int bt = 0; bt < 4; ++bt) {
        int row = wc * 64 + bt * 16 + (l & 15);
        int off = row * 128 + ((ks * 4 + (l >> 4)) ^ (row & 7)) * 16;
        bh[bt] = *(const short8*)(((const char*)Bh) + off);
        bl[bt] = *(const short8*)(((const char*)Bl) + off);
      }
#pragma unroll
      for (int ot = 0; ot < 4; ++ot)
#pragma unroll
        for (int bt = 0; bt < 4; ++bt) {
          acc[ot][bt] = __builtin_amdgcn_mfma_f32_16x16x32_bf16(ah[ot], bh[bt], acc[ot][bt], 0, 0, 0);
          acc[ot][bt] = __builtin_amdgcn_mfma_f32_16x16x32_bf16(ah[ot], bl[bt], acc[ot][bt], 0, 0, 0);
          acc[ot][bt] = __builtin_amdgcn_mfma_f32_16x16x32_bf16(al[ot], bh[bt], acc[ot][bt], 0, 0, 0);
        }
    }
    __syncthreads();
  }
  // fused L2-norm epilogue: each wave's wr half = one 64-dim head
  int head = (o0 >> 6) + wr;
#pragma unroll
  for (int bt = 0; bt < 4; ++bt) {
    float ss = 0.f;
#pragma unroll
    for (int ot = 0; ot < 4; ++ot)
#pragma unroll
      for (int r = 0; r < 4; ++r) ss += acc[ot][bt][r] * acc[ot][bt][r];
    ss += __shfl_xor(ss, 16, 64);
    ss += __shfl_xor(ss, 32, 64);
    float sc = 1.f / fmaxf(sqrtf(ss), 1e-12f);
    int loc = loc0 + wc * 64 + bt * 16 + (l & 15);
    size_t vecbase = (((size_t)(b * NHEADS + head)) * LLOC + loc) * DH;
#pragma unroll
    for (int ot = 0; ot < 4; ++ot)
#pragma unroll
      for (int r = 0; r < 4; ++r) {
        int d = ot * 16 + (l >> 4) * 4 + r;
        float v = acc[ot][bt][r] * sc;
        dst[vecbase + d] = v;
        if (Qb) Qb[vecbase + ((((d >> 3) ^ (loc & 7)) << 3) | (d & 7))] = f2bf(v);
      }
  }
}

// ---------------------------------------------------------------------------
// single-pass bf16 MFMA GEMM.  mode 3: -> V bf16 [bh][loc][64]
//                              mode 2: -> CO f32 [b][c][loc]
__global__ __launch_bounds__(256) void k_mfma1(int mode,
    const unsigned short* __restrict__ W, const unsigned short* __restrict__ X,
    float* __restrict__ outF, unsigned short* __restrict__ outU) {
  int b = blockIdx.z;
  int o0 = blockIdx.y * 128, loc0 = blockIdx.x * 128;
  int t = threadIdx.x, l = t & 63, w = t >> 6;
  int wr = w >> 1, wc = w & 1;
  __shared__ unsigned short Asm[128*64], Bsm[128*64];
  f32x4 acc[4][4];
#pragma unroll
  for (int i = 0; i < 4; ++i)
#pragma unroll
    for (int j = 0; j < 4; ++j) acc[i][j] = (f32x4){0.f, 0.f, 0.f, 0.f};
  const char* Wc = (const char*)W;
  const char* Xc = (const char*)(X + (size_t)b * LLOC * 512);
  int srow = l >> 3;
  int schunk = (l & 7) ^ srow;
  for (int kt = 0; kt < 8; ++kt) {
    int kb = kt * 128;
#pragma unroll
    for (int j = 0; j < 4; ++j) {
      int r = w * 32 + j * 8;
      GLOAD_LDS(Wc + (size_t)(o0 + r + srow) * 1024 + kb + schunk * 16,
                ((char*)Asm) + r * 128);
      GLOAD_LDS(Xc + (size_t)(loc0 + r + srow) * 1024 + kb + schunk * 16,
                ((char*)Bsm) + r * 128);
    }
    __syncthreads();
#pragma unroll
    for (int ks = 0; ks < 2; ++ks) {
      short8 af[4], bf[4];
#pragma unroll
      for (int ot = 0; ot < 4; ++ot) {
        int row = wr * 64 + ot * 16 + (l & 15);
        af[ot] = *(const short8*)(((const char*)Asm) + row * 128 + (((ks*4 + (l>>4)) ^ (row&7)) * 16));
      }
#pragma unroll
      for (int bt = 0; bt < 4; ++bt) {
        int row = wc * 64 + bt * 16 + (l & 15);
        bf[bt] = *(const short8*)(((const char*)Bsm) + row * 128 + (((ks*4 + (l>>4)) ^ (row&7)) * 16));
      }
#pragma unroll
      for (int ot = 0; ot < 4; ++ot)
#pragma unroll
        for (int bt = 0; bt < 4; ++bt)
          acc[ot][bt] = __builtin_amdgcn_mfma_f32_16x16x32_bf16(af[ot], bf[bt], acc[ot][bt], 0, 0, 0);
    }
    __syncthreads();
  }
#pragma unroll
  for (int ot = 0; ot < 4; ++ot) {
    int ob = o0 + wr * 64 + ot * 16 + (l >> 4) * 4;
#pragma unroll
    for (int bt = 0; bt < 4; ++bt) {
      int loc = loc0 + wc * 64 + bt * 16 + (l & 15);
#pragma unroll
      for (int r = 0; r < 4; ++r) {
        int o = ob + r;
        float v = acc[ot][bt][r];
        if (mode == 2)
          outF[((size_t)b * CC + o) * LLOC + loc] = v;
        else
          outU[(((size_t)(b * NHEADS + (o >> 6))) * LLOC + loc) * DH + (o & 63)] = f2bf(v);
      }
    }
  }
}

// ---------------------------------------------------------------------------
// partial min L1 distance: 1 key/thread as 32 f32x2 pinned in VGPRs via
// opaque asm. Queries read as float4 (b128). v_pk_add_f32 + v_add abs().
// grid (9 key-chunks of 256, 64 rows, 4 q-chunks of 72), block 256
__global__ __launch_bounds__(256) void k_mindist(const float* __restrict__ K,
    const float* __restrict__ Q, const int* __restrict__ idxRand,
    float* __restrict__ mindP) {
  int chunk = blockIdx.x, row = blockIdx.y, jz = blockIdx.z;
  __shared__ float qs[72][64];
  int t = threadIdx.x;
  int kk = chunk * 256 + t;
  f32x2 kv[32];
  const f32x2* kp = (const f32x2*)&K[((size_t)row * LLOC + kk) * 64];
#pragma unroll
  for (int d = 0; d < 32; ++d) kv[d] = kp[d];
#pragma unroll
  for (int d = 0; d < 32; ++d) asm volatile("" : "+v"(kv[d]));
  for (int e = t; e < 72 * 16; e += 256) {
    int j = e >> 4, t4 = (e & 15) * 4;
    int qi = idxRand[row * TKSEL + jz * 72 + j];
    *(float4*)&qs[j][t4] = *(const float4*)&Q[((size_t)row * LLOC + qi) * 64 + t4];
  }
  __syncthreads();
  float best = 3.402823e38f;
  for (int j = 0; j < 72; ++j) {
    const float4* q4 = (const float4*)&qs[j][0];
    float s0 = 0.f, s1 = 0.f, s2 = 0.f, s3 = 0.f;
#pragma unroll
    for (int d = 0; d < 4; ++d) {
      float4 qa = q4[d], qb = q4[4 + d], qc = q4[8 + d], qd = q4[12 + d];
      f32x2 qa0 = {qa.x, qa.y}, qa1 = {qa.z, qa.w};
      f32x2 qb0 = {qb.x, qb.y}, qb1 = {qb.z, qb.w};
      f32x2 qc0 = {qc.x, qc.y}, qc1 = {qc.z, qc.w};
      f32x2 qd0 = {qd.x, qd.y}, qd1 = {qd.z, qd.w};
      f32x2 a0, a1, b0, b1, c0, c1, e0, e1;
      asm("v_pk_add_f32 %0, %1, %2 neg_lo:[0,1] neg_hi:[0,1]" : "=v"(a0) : "v"(kv[2*d]),      "v"(qa0));
      asm("v_pk_add_f32 %0, %1, %2 neg_lo:[0,1] neg_hi:[0,1]" : "=v"(a1) : "v"(kv[2*d + 1]),  "v"(qa1));
      asm("v_pk_add_f32 %0, %1, %2 neg_lo:[0,1] neg_hi:[0,1]" : "=v"(b0) : "v"(kv[8 + 2*d]),  "v"(qb0));
      asm("v_pk_add_f32 %0, %1, %2 neg_lo:[0,1] neg_hi:[0,1]" : "=v"(b1) : "v"(kv[8 + 2*d + 1]), "v"(qb1));
      asm("v_pk_add_f32 %0, %1, %2 neg_lo:[0,1] neg_hi:[0,1]" : "=v"(c0) : "v"(kv[16 + 2*d]), "v"(qc0));
      asm("v_pk_add_f32 %0, %1, %2 neg_lo:[0,1] neg_hi:[0,1]" : "=v"(c1) : "v"(kv[16 + 2*d + 1]), "v"(qc1));
      asm("v_pk_add_f32 %0, %1, %2 neg_lo:[0,1] neg_hi:[0,1]" : "=v"(e0) : "v"(kv[24 + 2*d]), "v"(qd0));
      asm("v_pk_add_f32 %0, %1, %2 neg_lo:[0,1] neg_hi:[0,1]" : "=v"(e1) : "v"(kv[24 + 2*d + 1]), "v"(qd1));
      asm("v_add_f32 %0, abs(%1), %0" : "+v"(s0) : "v"(a0.x));
      asm("v_add_f32 %0, abs(%1), %0" : "+v"(s0) : "v"(a0.y));
      asm("v_add_f32 %0, abs(%1), %0" : "+v"(s0) : "v"(a1.x));
      asm("v_add_f32 %0, abs(%1), %0" : "+v"(s0) : "v"(a1.y));
      asm("v_add_f32 %0, abs(%1), %0" : "+v"(s1) : "v"(b0.x));
      asm("v_add_f32 %0, abs(%1), %0" : "+v"(s1) : "v"(b0.y));
      asm("v_add_f32 %0, abs(%1), %0" : "+v"(s1) : "v"(b1.x));
      asm("v_add_f32 %0, abs(%1), %0" : "+v"(s1) : "v"(b1.y));
      asm("v_add_f32 %0, abs(%1), %0" : "+v"(s2) : "v"(c0.x));
      asm("v_add_f32 %0, abs(%1), %0" : "+v"(s2) : "v"(c0.y));
      asm("v_add_f32 %0, abs(%1), %0" : "+v"(s2) : "v"(c1.x));
      asm("v_add_f32 %0, abs(%1), %0" : "+v"(s2) : "v"(c1.y));
      asm("v_add_f32 %0, abs(%1), %0" : "+v"(s3) : "v"(e0.x));
      asm("v_add_f32 %0, abs(%1), %0" : "+v"(s3) : "v"(e0.y));
      asm("v_add_f32 %0, abs(%1), %0" : "+v"(s3) : "v"(e1.x));
      asm("v_add_f32 %0, abs(%1), %0" : "+v"(s3) : "v"(e1.y));
    }
    best = fminf(best, (s0 + s1) + (s2 + s3));
  }
  mindP[((size_t)jz * BH + row) * LLOC + kk] = best;
}

// ---------------------------------------------------------------------------
// exact rank selection over folded min of the 4 partials
__global__ __launch_bounds__(256) void k_select(const float* __restrict__ mindP,
                                                int* __restrict__ sel) {
  int row = blockIdx.y;
  int i = blockIdx.x * 256 + threadIdx.x;
  __shared__ float dd[LLOC];
  const size_t stride = (size_t)BH * LLOC;
  for (int e = threadIdx.x; e < LLOC; e += 256) {
    size_t o = (size_t)row * LLOC + e;
    float m0 = fminf(mindP[o], mindP[o + stride]);
    float m1 = fminf(mindP[o + 2 * stride], mindP[o + 3 * stride]);
    dd[e] = fminf(m0, m1);
  }
  __syncthreads();
  float di = dd[i];
  int rank = 0;
  for (int j = 0; j < LLOC; j += 4) {
    float4 dj = *(const float4*)&dd[j];
    rank += (dj.x < di) || (dj.x == di && (j+0) < i);
    rank += (dj.y < di) || (dj.y == di && (j+1) < i);
    rank += (dj.z < di) || (dj.z == di && (j+2) < i);
    rank += (dj.w < di) || (dj.w == di && (j+3) < i);
  }
  if (rank < TKSEL) sel[row * TKSEL + rank] = i;
}

// ---------------------------------------------------------------------------
// gather selected K (f32 -> swizzled bf16 [row][288][64]) and V transposed
// (bf16 [row][64][288]) for MFMA attention
__global__ __launch_bounds__(256) void k_gather(const float* __restrict__ K,
    const unsigned short* __restrict__ Vb, const int* __restrict__ sel,
    unsigned short* __restrict__ Kc, unsigned short* __restrict__ Vt) {
  int row = blockIdx.x;
  int d = threadIdx.x & 63;
  for (int ki = threadIdx.x >> 6; ki < TKSEL; ki += 4) {
    int k = sel[row * TKSEL + ki];
    float kv = K[((size_t)row * LLOC + k) * 64 + d];
    Kc[((size_t)row * TKSEL + ki) * 64 + (((d >> 3) ^ (ki & 7)) << 3) + (d & 7)] = f2bf(kv);
    Vt[((size_t)row * 64 + d) * TKSEL + ki] = Vb[((size_t)row * LLOC + k) * 64 + d];
  }
}

// ---------------------------------------------------------------------------
// MFMA attention: block=(36 q-tiles of 64, 64 rows), 4 waves x 16 q.
// S^T[k][q]=mfma(K,Q); exp in-reg; P bounced via per-wave LDS; O^T[d][q]=mfma(V^T,P).
// No max-subtraction (s in [-1,1]). Output bf16 AOb[b][loc][h*64+d].
__global__ __launch_bounds__(256) void k_attn_mfma(
    const unsigned short* __restrict__ Qb, const unsigned short* __restrict__ Kc,
    const unsigned short* __restrict__ Vt, unsigned short* __restrict__ AOb) {
  int row = blockIdx.y, q0 = blockIdx.x * 64;
  int t = threadIdx.x, l = t & 63, w = t >> 6;
  int q15 = l & 15, l4 = l >> 4;
  __shared__ unsigned short Qsm[64 * 64];    // swizzled chunks (from Qb)
  __shared__ unsigned short Ksm[96 * 64];    // swizzled chunks (from Kc)
  __shared__ unsigned short Vsm[64 * 120];   // V^T rows padded to 120
  __shared__ unsigned short Psm[4 * 512];    // per-wave 16q x 32k, slot-swizzled

  f32x4 oacc[4];
#pragma unroll
  for (int dt = 0; dt < 4; ++dt) oacc[dt] = (f32x4){0.f, 0.f, 0.f, 0.f};
  float lsum = 0.f;

  // stage Q tile once (global pre-swizzled -> linear copy)
  const char* QbC = (const char*)(Qb + ((size_t)row * LLOC + q0) * 64);
#pragma unroll
  for (int i = 0; i < 2; ++i)
    GLOAD_LDS(QbC + (size_t)(i * 256 + w * 64 + l) * 16, ((char*)Qsm) + (i * 256 + w * 64) * 16);

  for (int c = 0; c < 3; ++c) {
    // stage K chunk (pre-swizzled -> linear)
    const char* KcC = (const char*)(Kc + (((size_t)row * TKSEL) + c * 96) * 64);
#pragma unroll
    for (int i = 0; i < 3; ++i)
      GLOAD_LDS(KcC + (size_t)(i * 256 + w * 64 + l) * 16, ((char*)Ksm) + (i * 256 + w * 64) * 16);
    // stage V^T chunk into padded rows (reg-staged)
#pragma unroll
    for (int i = 0; i < 3; ++i) {
      int s = i * 256 + t;             // 0..767
      int d = s / 12, j = s % 12;
      uint4 v = *(const uint4*)(Vt + ((size_t)row * 64 + d) * TKSEL + c * 96 + j * 8);
      *(uint4*)((char*)Vsm + d * 240 + j * 16) = v;
    }
    __syncthreads();

    // QK^T: S^T[k][q], 6 k-tiles
    f32x4 sacc[6];
#pragma unroll
    for (int kt = 0; kt < 6; ++kt) sacc[kt] = (f32x4){0.f, 0.f, 0.f, 0.f};
#pragma unroll
    for (int ks = 0; ks < 2; ++ks) {
      int qrow = w * 16 + q15;
      short8 qf = *(const short8*)(Qsm + qrow * 64 + (((ks * 4 + l4) ^ (qrow & 7)) << 3));
#pragma unroll
      for (int kt = 0; kt < 6; ++kt) {
        int krow = kt * 16 + q15;
        short8 kf = *(const short8*)(Ksm + krow * 64 + (((ks * 4 + l4) ^ (krow & 7)) << 3));
        sacc[kt] = __builtin_amdgcn_mfma_f32_16x16x32_bf16(kf, qf, sacc[kt], 0, 0, 0);
      }
    }

    // softmax exp + PV per 32-key sub-chunk
    char* Pw = (char*)(Psm + w * 512);
#pragma unroll
    for (int s3 = 0; s3 < 3; ++s3) {
#pragma unroll
      for (int h2 = 0; h2 < 2; ++h2) {
        int kt = 2 * s3 + h2;
        float p0 = expf(sacc[kt][0]), p1 = expf(sacc[kt][1]);
        float p2 = expf(sacc[kt][2]), p3 = expf(sacc[kt][3]);
        lsum += (p0 + p1) + (p2 + p3);
        unsigned lo = (unsigned)f2bf(p0) | ((unsigned)f2bf(p1) << 16);
        unsigned hi = (unsigned)f2bf(p2) | ((unsigned)f2bf(p3) << 16);
        int sl = (h2 * 4 + l4) ^ ((q15 & 3) << 1);
        *(uint2*)(Pw + q15 * 64 + sl * 8) = make_uint2(lo, hi);
      }
      short8 pB = *(const short8*)(Pw + q15 * 64 + (((2 * l4) ^ ((q15 & 3) << 1)) * 8));
#pragma unroll
      for (int dt = 0; dt < 4; ++dt) {
        short8 vA = *(const short8*)(Vsm + (dt * 16 + q15) * 120 + s3 * 32 + l4 * 8);
        oacc[dt] = __builtin_amdgcn_mfma_f32_16x16x32_bf16(vA, pB, oacc[dt], 0, 0, 0);
      }
    }
    __syncthreads();
  }

  // normalize and write
  lsum += __shfl_xor(lsum, 16, 64);
  lsum += __shfl_xor(lsum, 32, 64);
  float inv = 1.f / lsum;
  int bq = row >> 3, hq = row & 7;
  int loc = q0 + w * 16 + q15;
  unsigned short* op = AOb + ((size_t)bq * LLOC + loc) * 512 + hq * 64;
#pragma unroll
  for (int dt = 0; dt < 4; ++dt) {
    unsigned w0 = (unsigned)f2bf(oacc[dt][0] * inv) | ((unsigned)f2bf(oacc[dt][1] * inv) << 16);
    unsigned w1 = (unsigned)f2bf(oacc[dt][2] * inv) | ((unsigned)f2bf(oacc[dt][3] * inv) << 16);
    *(uint2*)(op + dt * 16 + l4 * 4) = make_uint2(w0, w1);
  }
}

// ---------------------------------------------------------------------------
// FUSED final: channel-LN stats over CO + out = gamma*LN(CO)*g + qsrc.
// One block = 64 locs x all 512 c; phase 2 re-read is L3-hot.
__global__ __launch_bounds__(256) void k_final_f(const float* __restrict__ CO,
    const float* __restrict__ g, const float* __restrict__ gamma,
    const float* __restrict__ qsrc, float* __restrict__ out) {
  int b = blockIdx.y, loc0 = blockIdx.x * 64;
  int t = threadIdx.x, lx = t & 63, cg = t >> 6;
  const float* cb = CO + (size_t)b * CC * LLOC;
  float s = 0.f, s2 = 0.f;
  for (int c = cg; c < CC; c += 4) {
    float v = cb[(size_t)c * LLOC + loc0 + lx];
    s += v; s2 += v * v;
  }
  __shared__ float sh[2][256];
  __shared__ float mS[64], rS[64];
  sh[0][t] = s; sh[1][t] = s2;
  __syncthreads();
  if (t < 64) {
    float S  = sh[0][t] + sh[0][t+64] + sh[0][t+128] + sh[0][t+192];
    float S2 = sh[1][t] + sh[1][t+64] + sh[1][t+128] + sh[1][t+192];
    float mean = S * (1.f/512.f);
    float var  = S2 * (1.f/512.f) - mean * mean;
    mS[t] = mean;
    rS[t] = 1.f / sqrtf(var + 1e-5f);
  }
  __syncthreads();
  float mean = mS[lx], rstd = rS[lx];
  float ga = gamma[0];
  size_t bbase = (size_t)b * CC * LLOC;
  for (int c = cg; c < CC; c += 4) {
    size_t off = (size_t)c * LLOC + loc0 + lx;
    float v = cb[off];
    out[bbase + off] = ga * (v - mean) * rstd * g[c] + qsrc[bbase + off];
  }
}

// ---------------------------------------------------------------------------
extern "C" void kernel_launch(void* const* d_in, const int* in_sizes, int n_in,
                              void* d_out, int out_size, void* d_ws, size_t ws_size,
                              hipStream_t stream) {
  const float* qsrc  = (const float*)d_in[0];
  const float* ctx   = (const float*)d_in[1];
  const float* g_ctx = (const float*)d_in[2];
  const float* g_qs  = (const float*)d_in[3];
  const float* g_out = (const float*)d_in[4];
  const float* w_kv  = (const float*)d_in[5];
  const float* w_q   = (const float*)d_in[6];
  const float* w_out = (const float*)d_in[7];
  const float* gamma = (const float*)d_in[8];
  float* out = (float*)d_out;

  // workspace layout; total ~171 MiB
  float* ws = (float*)d_ws;
  int*   idxRand  = (int*)(ws + 73728);      // 18432
  int*   sel      = (int*)(ws + 92160);      // 18432
  float* Q  = ws + 258048;                   // 9437184 f
  float* K  = Q + 9437184;                   // 9437184 f
  unsigned short* usb = (unsigned short*)(K + 9437184);
  unsigned short* Vb     = usb;              // 9437184 us
  unsigned short* Xt_hi  = Vb + 9437184;     // 9437184 us (later: AOb)
  unsigned short* Xt_lo  = Xt_hi + 9437184;  // 9437184 us
  unsigned short* Wkv_hi = Xt_lo + 9437184;  // 524288 us
  unsigned short* Wkv_lo = Wkv_hi + 524288;  // 524288 us
  unsigned short* Wq_hi  = Wkv_lo + 524288;  // 262144 us
  unsigned short* Wq_lo  = Wq_hi + 262144;   // 262144 us
  unsigned short* Wo_hi  = Wq_lo + 262144;   // 262144 us
  unsigned short* Wo_lo  = Wo_hi + 262144;   // 262144 us
  float* mindP = (float*)(Wo_lo + 262144);   // 4*64*2304 = 589824 f
  unsigned short* Kc = (unsigned short*)(mindP + 589824);  // 1179648 us
  unsigned short* Vt = Kc + 1179648;                       // 1179648 us
  unsigned short* Qb = Vt + 1179648;                       // 9437184 us
  float* CO = Q;                             // Q dead after attention

  k_threefry<<<72, 256, 0, stream>>>(idxRand);
  k_prep_w_all<<<2048, 256, 0, stream>>>(w_kv, w_q, w_out, g_ctx, g_qs,
                                         Wkv_hi, Wkv_lo, Wq_hi, Wq_lo, Wo_hi, Wo_lo);
  k_prep_xf<<<dim3(36, 8), 256, 0, stream>>>(ctx, Xt_hi, Xt_lo);
  k_mfma3<<<dim3(18, 4, 8), 256, 0, stream>>>(Wkv_hi, Wkv_lo, Xt_hi, Xt_lo, K, nullptr);
  k_mfma1<<<dim3(18, 4, 8), 256, 0, stream>>>(3, Wkv_hi + 512*512, Xt_hi, nullptr, Vb);
  k_prep_xf<<<dim3(36, 8), 256, 0, stream>>>(qsrc, Xt_hi, Xt_lo);
  k_mfma3<<<dim3(18, 4, 8), 256, 0, stream>>>(Wq_hi, Wq_lo, Xt_hi, Xt_lo, Q, Qb);
  k_mindist<<<dim3(9, 64, 4), 256, 0, stream>>>(K, Q, idxRand, mindP);
  k_select<<<dim3(9, 64), 256, 0, stream>>>(mindP, sel);
  k_gather<<<64, 256, 0, stream>>>(K, Vb, sel, Kc, Vt);
  k_attn_mfma<<<dim3(36, 64), 256, 0, stream>>>(Qb, Kc, Vt, Xt_hi);  // AOb = Xt_hi
  k_mfma1<<<dim3(18, 4, 8), 256, 0, stream>>>(2, Wo_hi, Xt_hi, CO, nullptr);
  k_final_f<<<dim3(36, 8), 256, 0, stream>>>(CO, g_out, gamma, qsrc, out);
}

// Round 17
// 639.773 us; speedup vs baseline: 1.0120x; 1.0120x over previous
//
#include <hip/hip_runtime.h>
#include <hip/hip_bf16.h>

// Problem constants
#define BB 8
#define CC 512
#define LLOC 2304        // 48*48
#define NHEADS 8
#define DH 64
#define BH 64            // BB*NHEADS
#define TKSEL 288        // 2304/8

typedef unsigned int u32;
typedef short short8 __attribute__((ext_vector_type(8)));
typedef float f32x4 __attribute__((ext_vector_type(4)));
typedef float f32x2 __attribute__((ext_vector_type(2)));

__device__ inline unsigned short f2bf(float f) {
  unsigned u = __float_as_uint(f);
  u += 0x7FFFu + ((u >> 16) & 1u);
  return (unsigned short)(u >> 16);
}
__device__ inline float b2f(unsigned short h) {
  return __uint_as_float(((unsigned)h) << 16);
}

// global -> LDS direct async copy, 16B/lane; dst = wave-uniform base (+lane*16 implicit)
#define GLOAD_LDS(gsrc, ldst) \
  __builtin_amdgcn_global_load_lds((const __attribute__((address_space(1))) u32*)(gsrc), \
                                   (__attribute__((address_space(3))) u32*)(ldst), 16, 0, 0)

// ---------------------------------------------------------------------------
__device__ inline void tf2x32(unsigned ks0, unsigned ks1, unsigned x0, unsigned x1,
                              unsigned& y0, unsigned& y1) {
  unsigned ks2 = ks0 ^ ks1 ^ 0x1BD11BDAu;
#define TF_R(r) { x0 += x1; x1 = (x1 << (r)) | (x1 >> (32-(r))); x1 ^= x0; }
  x0 += ks0; x1 += ks1;
  TF_R(13) TF_R(15) TF_R(26) TF_R(6)
  x0 += ks1; x1 += ks2 + 1u;
  TF_R(17) TF_R(29) TF_R(16) TF_R(24)
  x0 += ks2; x1 += ks0 + 2u;
  TF_R(13) TF_R(15) TF_R(26) TF_R(6)
  x0 += ks0; x1 += ks1 + 3u;
  TF_R(17) TF_R(29) TF_R(16) TF_R(24)
  x0 += ks1; x1 += ks2 + 4u;
  TF_R(13) TF_R(15) TF_R(26) TF_R(6)
  x0 += ks2; x1 += ks0 + 5u;
#undef TF_R
  y0 = x0; y1 = x1;
}

// JAX randint(key(42), (64,288), 0, 2304), partitionable threefry, XOR-fold
__global__ __launch_bounds__(256) void k_threefry(int* __restrict__ idxRand) {
  unsigned i = blockIdx.x * 256 + threadIdx.x;   // 0..18431
  if (i >= 18432u) return;
  unsigned a0, a1, b0, b1;
  tf2x32(0u, 42u, 0u, 0u, a0, a1);   // k1
  tf2x32(0u, 42u, 0u, 1u, b0, b1);   // k2
  unsigned h0, h1, l0, l1;
  tf2x32(a0, a1, 0u, i, h0, h1);
  tf2x32(b0, b1, 0u, i, l0, l1);
  unsigned h = h0 ^ h1;
  unsigned l = l0 ^ l1;
  const unsigned span = 2304u;
  idxRand[i] = (int)(((h % span) * 256u + (l % span)) % span);
}

// ---------------------------------------------------------------------------
// All three W -> bf16 hi/lo conversions in one launch (range dispatch).
__global__ __launch_bounds__(256) void k_prep_w_all(
    const float* __restrict__ w_kv, const float* __restrict__ w_q,
    const float* __restrict__ w_out, const float* __restrict__ g_ctx,
    const float* __restrict__ g_qs,
    unsigned short* __restrict__ Wkv_hi, unsigned short* __restrict__ Wkv_lo,
    unsigned short* __restrict__ Wq_hi,  unsigned short* __restrict__ Wq_lo,
    unsigned short* __restrict__ Wo_hi,  unsigned short* __restrict__ Wo_lo) {
  int i2 = (blockIdx.x * 256 + threadIdx.x) * 2;
  const float* W; const float* G;
  unsigned short *Wh, *Wl; int base;
  if (i2 < 524288) { W = w_kv; G = g_ctx; Wh = Wkv_hi; Wl = Wkv_lo; base = 0; }
  else if (i2 < 786432) { W = w_q; G = g_qs; Wh = Wq_hi; Wl = Wq_lo; base = 524288; }
  else { W = w_out; G = nullptr; Wh = Wo_hi; Wl = Wo_lo; base = 786432; }
  int i = i2 - base;
  int c = i & 511;
  float2 w2 = *(const float2*)&W[i];
  float g0 = G ? G[c] : 1.f, g1 = G ? G[c + 1] : 1.f;
  float f0 = w2.x * g0, f1 = w2.y * g1;
  unsigned short h0 = f2bf(f0), h1 = f2bf(f1);
  unsigned short q0 = f2bf(f0 - b2f(h0)), q1 = f2bf(f1 - b2f(h1));
  *(unsigned*)&Wh[i] = (unsigned)h0 | ((unsigned)h1 << 16);
  *(unsigned*)&Wl[i] = (unsigned)q0 | ((unsigned)q1 << 16);
}

// ---------------------------------------------------------------------------
// FUSED channel-LN stats + normalize + transpose + bf16 hi/lo split:
// X[b][c][loc] -> Xt[b][loc][512]. One block = 64 locs x all 512 c.
__global__ __launch_bounds__(256) void k_prep_xf(const float* __restrict__ X,
    unsigned short* __restrict__ Xh, unsigned short* __restrict__ Xl) {
  int b = blockIdx.y, loc0 = blockIdx.x * 64;
  int t = threadIdx.x, lx = t & 63, cg = t >> 6;
  const float* xb = X + (size_t)b * CC * LLOC;
  float s = 0.f, s2 = 0.f;
  for (int c = cg; c < CC; c += 4) {
    float v = xb[(size_t)c * LLOC + loc0 + lx];
    s += v; s2 += v * v;
  }
  __shared__ float sh[2][256];
  __shared__ float mS[64], rS[64];
  sh[0][t] = s; sh[1][t] = s2;
  __syncthreads();
  if (t < 64) {
    float S  = sh[0][t] + sh[0][t+64] + sh[0][t+128] + sh[0][t+192];
    float S2 = sh[1][t] + sh[1][t+64] + sh[1][t+128] + sh[1][t+192];
    float mean = S * (1.f/512.f);
    float var  = S2 * (1.f/512.f) - mean * mean;
    mS[t] = mean;
    rS[t] = 1.f / sqrtf(var + 1e-5f);
  }
  __syncthreads();
  __shared__ float sm[64][65];
  float mean = mS[lx], rstd = rS[lx];
  int loc = t >> 2, cs = (t & 3) * 16;
  for (int cc = 0; cc < 8; ++cc) {
    int c0 = cc * 64;
#pragma unroll
    for (int i = 0; i < 16; ++i) {
      int c = cg + i * 4;
      float v = xb[(size_t)(c0 + c) * LLOC + loc0 + lx];
      sm[c][lx] = (v - mean) * rstd;
    }
    __syncthreads();
    unsigned uh[8], ul[8];
#pragma unroll
    for (int j = 0; j < 8; ++j) {
      float f0 = sm[cs + j*2][loc];
      float f1 = sm[cs + j*2 + 1][loc];
      unsigned short h0 = f2bf(f0), h1 = f2bf(f1);
      unsigned short q0 = f2bf(f0 - b2f(h0)), q1 = f2bf(f1 - b2f(h1));
      uh[j] = (unsigned)h0 | ((unsigned)h1 << 16);
      ul[j] = (unsigned)q0 | ((unsigned)q1 << 16);
    }
    size_t base = ((size_t)b * LLOC + loc0 + loc) * 512 + c0 + cs;
    *(uint4*)(Xh + base)     = make_uint4(uh[0], uh[1], uh[2], uh[3]);
    *(uint4*)(Xh + base + 8) = make_uint4(uh[4], uh[5], uh[6], uh[7]);
    *(uint4*)(Xl + base)     = make_uint4(ul[0], ul[1], ul[2], ul[3]);
    *(uint4*)(Xl + base + 8) = make_uint4(ul[4], ul[5], ul[6], ul[7]);
    __syncthreads();
  }
}

// ---------------------------------------------------------------------------
// 3-pass split-bf16 MFMA GEMM (~f32 precision) with FUSED L2-NORM epilogue:
// dst = l2norm(W*X^T) over each 64-dim head; K/Q layout out.
// If Qb != nullptr, also emit swizzled bf16 copy (for MFMA attention).
__global__ __launch_bounds__(256) void k_mfma3(
    const unsigned short* __restrict__ Wh, const unsigned short* __restrict__ Wl,
    const unsigned short* __restrict__ Xh, const unsigned short* __restrict__ Xl,
    float* __restrict__ dst, unsigned short* __restrict__ Qb) {
  int b = blockIdx.z;
  int o0 = blockIdx.y * 128, loc0 = blockIdx.x * 128;
  int t = threadIdx.x, l = t & 63, w = t >> 6;
  int wr = w >> 1, wc = w & 1;
  __shared__ unsigned short Ah[128*64], Al[128*64], Bh[128*64], Bl[128*64];
  f32x4 acc[4][4];
#pragma unroll
  for (int i = 0; i < 4; ++i)
#pragma unroll
    for (int j = 0; j < 4; ++j) acc[i][j] = (f32x4){0.f, 0.f, 0.f, 0.f};

  const char* WhC = (const char*)Wh;
  const char* WlC = (const char*)Wl;
  const char* XhC = (const char*)(Xh + (size_t)b * LLOC * 512);
  const char* XlC = (const char*)(Xl + (size_t)b * LLOC * 512);
  int srow = l >> 3;
  int schunk = (l & 7) ^ srow;

  for (int kt = 0; kt < 8; ++kt) {
    int kb = kt * 128;
#pragma unroll
    for (int j = 0; j < 4; ++j) {
      int r = w * 32 + j * 8;
      size_t arow = (size_t)(o0 + r + srow) * 1024 + kb + schunk * 16;
      size_t brow = (size_t)(loc0 + r + srow) * 1024 + kb + schunk * 16;
      GLOAD_LDS(WhC + arow, ((char*)Ah) + r * 128);
      GLOAD_LDS(WlC + arow, ((char*)Al) + r * 128);
      GLOAD_LDS(XhC + brow, ((char*)Bh) + r * 128);
      GLOAD_LDS(XlC + brow, ((char*)Bl) + r * 128);
    }
    __syncthreads();
#pragma unroll
    for (int ks = 0; ks < 2; ++ks) {
      short8 ah[4], al[4], bh[4], bl[4];
#pragma unroll
      for (int ot = 0; ot < 4; ++ot) {
        int row = wr * 64 + ot * 16 + (l & 15);
        int off = row * 128 + ((ks * 4 + (l >> 4)) ^ (row & 7)) * 16;
        ah[ot] = *(const short8*)(((const char*)Ah) + off);
        al[ot] = *(const short8*)(((const char*)Al) + off);
      }
#pragma unroll
      for (int bt = 0; bt < 4; ++bt) {
        int row = wc * 64 + bt * 16 + (l & 15);
        int off = row * 128 + ((ks * 4 + (l >> 4)) ^ (row & 7)) * 16;
        bh[bt] = *(const short8*)(((const char*)Bh) + off);
        bl[bt] = *(const short8*)(((const char*)Bl) + off);
      }
#pragma unroll
      for (int ot = 0; ot < 4; ++ot)
#pragma unroll
        for (int bt = 0; bt < 4; ++bt) {
          acc[ot][bt] = __builtin_amdgcn_mfma_f32_16x16x32_bf16(ah[ot], bh[bt], acc[ot][bt], 0, 0, 0);
          acc[ot][bt] = __builtin_amdgcn_mfma_f32_16x16x32_bf16(ah[ot], bl[bt], acc[ot][bt], 0, 0, 0);
          acc[ot][bt] = __builtin_amdgcn_mfma_f32_16x16x32_bf16(al[ot], bh[bt], acc[ot][bt], 0, 0, 0);
        }
    }
    __syncthreads();
  }
  // fused L2-norm epilogue: each wave's wr half = one 64-dim head
  int head = (o0 >> 6) + wr;
#pragma unroll
  for (int bt = 0; bt < 4; ++bt) {
    float ss = 0.f;
#pragma unroll
    for (int ot = 0; ot < 4; ++ot)
#pragma unroll
      for (int r = 0; r < 4; ++r) ss += acc[ot][bt][r] * acc[ot][bt][r];
    ss += __shfl_xor(ss, 16, 64);
    ss += __shfl_xor(ss, 32, 64);
    float sc = 1.f / fmaxf(sqrtf(ss), 1e-12f);
    int loc = loc0 + wc * 64 + bt * 16 + (l & 15);
    size_t vecbase = (((size_t)(b * NHEADS + head)) * LLOC + loc) * DH;
#pragma unroll
    for (int ot = 0; ot < 4; ++ot)
#pragma unroll
      for (int r = 0; r < 4; ++r) {
        int d = ot * 16 + (l >> 4) * 4 + r;
        float v = acc[ot][bt][r] * sc;
        dst[vecbase + d] = v;
        if (Qb) Qb[vecbase + ((((d >> 3) ^ (loc & 7)) << 3) | (d & 7))] = f2bf(v);
      }
  }
}

// ---------------------------------------------------------------------------
// single-pass bf16 MFMA GEMM.  mode 3: -> V bf16 [bh][loc][64]
//                              mode 2: -> CO f32 [b][c][loc]
__global__ __launch_bounds__(256) void k_mfma1(int mode,
    const unsigned short* __restrict__ W, const unsigned short* __restrict__ X,
    float* __restrict__ outF, unsigned short* __restrict__ outU) {
  int b = blockIdx.z;
  int o0 = blockIdx.y * 128, loc0 = blockIdx.x * 128;
  int t = threadIdx.x, l = t & 63, w = t >> 6;
  int wr = w >> 1, wc = w & 1;
  __shared__ unsigned short Asm[128*64], Bsm[128*64];
  f32x4 acc[4][4];
#pragma unroll
  for (int i = 0; i < 4; ++i)
#pragma unroll
    for (int j = 0; j < 4; ++j) acc[i][j] = (f32x4){0.f, 0.f, 0.f, 0.f};
  const char* Wc = (const char*)W;
  const char* Xc = (const char*)(X + (size_t)b * LLOC * 512);
  int srow = l >> 3;
  int schunk = (l & 7) ^ srow;
  for (int kt = 0; kt < 8; ++kt) {
    int kb = kt * 128;
#pragma unroll
    for (int j = 0; j < 4; ++j) {
      int r = w * 32 + j * 8;
      GLOAD_LDS(Wc + (size_t)(o0 + r + srow) * 1024 + kb + schunk * 16,
                ((char*)Asm) + r * 128);
      GLOAD_LDS(Xc + (size_t)(loc0 + r + srow) * 1024 + kb + schunk * 16,
                ((char*)Bsm) + r * 128);
    }
    __syncthreads();
#pragma unroll
    for (int ks = 0; ks < 2; ++ks) {
      short8 af[4], bf[4];
#pragma unroll
      for (int ot = 0; ot < 4; ++ot) {
        int row = wr * 64 + ot * 16 + (l & 15);
        af[ot] = *(const short8*)(((const char*)Asm) + row * 128 + (((ks*4 + (l>>4)) ^ (row&7)) * 16));
      }
#pragma unroll
      for (int bt = 0; bt < 4; ++bt) {
        int row = wc * 64 + bt * 16 + (l & 15);
        bf[bt] = *(const short8*)(((const char*)Bsm) + row * 128 + (((ks*4 + (l>>4)) ^ (row&7)) * 16));
      }
#pragma unroll
      for (int ot = 0; ot < 4; ++ot)
#pragma unroll
        for (int bt = 0; bt < 4; ++bt)
          acc[ot][bt] = __builtin_amdgcn_mfma_f32_16x16x32_bf16(af[ot], bf[bt], acc[ot][bt], 0, 0, 0);
    }
    __syncthreads();
  }
#pragma unroll
  for (int ot = 0; ot < 4; ++ot) {
    int ob = o0 + wr * 64 + ot * 16 + (l >> 4) * 4;
#pragma unroll
    for (int bt = 0; bt < 4; ++bt) {
      int loc = loc0 + wc * 64 + bt * 16 + (l & 15);
#pragma unroll
      for (int r = 0; r < 4; ++r) {
        int o = ob + r;
        float v = acc[ot][bt][r];
        if (mode == 2)
          outF[((size_t)b * CC + o) * LLOC + loc] = v;
        else
          outU[(((size_t)(b * NHEADS + (o >> 6))) * LLOC + loc) * DH + (o & 63)] = f2bf(v);
      }
    }
  }
}

// ---------------------------------------------------------------------------
// partial min L1 distance: 1 key/thread as 32 f32x2 pinned in VGPRs via
// opaque asm. Queries read as f32x4 (b128); pairs extracted with
// __builtin_shufflevector (aligned sub-register, no v_mov copies).
// grid (9 key-chunks of 256, 64 rows, 4 q-chunks of 72), block 256
__global__ __launch_bounds__(256) void k_mindist(const float* __restrict__ K,
    const float* __restrict__ Q, const int* __restrict__ idxRand,
    float* __restrict__ mindP) {
  int chunk = blockIdx.x, row = blockIdx.y, jz = blockIdx.z;
  __shared__ float qs[72][64];
  int t = threadIdx.x;
  int kk = chunk * 256 + t;
  f32x2 kv[32];
  const f32x2* kp = (const f32x2*)&K[((size_t)row * LLOC + kk) * 64];
#pragma unroll
  for (int d = 0; d < 32; ++d) kv[d] = kp[d];
#pragma unroll
  for (int d = 0; d < 32; ++d) asm volatile("" : "+v"(kv[d]));
  for (int e = t; e < 72 * 16; e += 256) {
    int j = e >> 4, t4 = (e & 15) * 4;
    int qi = idxRand[row * TKSEL + jz * 72 + j];
    *(float4*)&qs[j][t4] = *(const float4*)&Q[((size_t)row * LLOC + qi) * 64 + t4];
  }
  __syncthreads();
  float best = 3.402823e38f;
  for (int j = 0; j < 72; ++j) {
    const f32x4* q4 = (const f32x4*)&qs[j][0];
    float s0 = 0.f, s1 = 0.f, s2 = 0.f, s3 = 0.f;
#pragma unroll
    for (int d = 0; d < 4; ++d) {
      f32x4 qa = q4[d], qb = q4[4 + d], qc = q4[8 + d], qd = q4[12 + d];
      f32x2 qa0 = __builtin_shufflevector(qa, qa, 0, 1);
      f32x2 qa1 = __builtin_shufflevector(qa, qa, 2, 3);
      f32x2 qb0 = __builtin_shufflevector(qb, qb, 0, 1);
      f32x2 qb1 = __builtin_shufflevector(qb, qb, 2, 3);
      f32x2 qc0 = __builtin_shufflevector(qc, qc, 0, 1);
      f32x2 qc1 = __builtin_shufflevector(qc, qc, 2, 3);
      f32x2 qd0 = __builtin_shufflevector(qd, qd, 0, 1);
      f32x2 qd1 = __builtin_shufflevector(qd, qd, 2, 3);
      f32x2 a0, a1, b0, b1, c0, c1, e0, e1;
      asm("v_pk_add_f32 %0, %1, %2 neg_lo:[0,1] neg_hi:[0,1]" : "=v"(a0) : "v"(kv[2*d]),      "v"(qa0));
      asm("v_pk_add_f32 %0, %1, %2 neg_lo:[0,1] neg_hi:[0,1]" : "=v"(a1) : "v"(kv[2*d + 1]),  "v"(qa1));
      asm("v_pk_add_f32 %0, %1, %2 neg_lo:[0,1] neg_hi:[0,1]" : "=v"(b0) : "v"(kv[8 + 2*d]),  "v"(qb0));
      asm("v_pk_add_f32 %0, %1, %2 neg_lo:[0,1] neg_hi:[0,1]" : "=v"(b1) : "v"(kv[8 + 2*d + 1]), "v"(qb1));
      asm("v_pk_add_f32 %0, %1, %2 neg_lo:[0,1] neg_hi:[0,1]" : "=v"(c0) : "v"(kv[16 + 2*d]), "v"(qc0));
      asm("v_pk_add_f32 %0, %1, %2 neg_lo:[0,1] neg_hi:[0,1]" : "=v"(c1) : "v"(kv[16 + 2*d + 1]), "v"(qc1));
      asm("v_pk_add_f32 %0, %1, %2 neg_lo:[0,1] neg_hi:[0,1]" : "=v"(e0) : "v"(kv[24 + 2*d]), "v"(qd0));
      asm("v_pk_add_f32 %0, %1, %2 neg_lo:[0,1] neg_hi:[0,1]" : "=v"(e1) : "v"(kv[24 + 2*d + 1]), "v"(qd1));
      asm("v_add_f32 %0, abs(%1), %0" : "+v"(s0) : "v"(a0.x));
      asm("v_add_f32 %0, abs(%1), %0" : "+v"(s0) : "v"(a0.y));
      asm("v_add_f32 %0, abs(%1), %0" : "+v"(s0) : "v"(a1.x));
      asm("v_add_f32 %0, abs(%1), %0" : "+v"(s0) : "v"(a1.y));
      asm("v_add_f32 %0, abs(%1), %0" : "+v"(s1) : "v"(b0.x));
      asm("v_add_f32 %0, abs(%1), %0" : "+v"(s1) : "v"(b0.y));
      asm("v_add_f32 %0, abs(%1), %0" : "+v"(s1) : "v"(b1.x));
      asm("v_add_f32 %0, abs(%1), %0" : "+v"(s1) : "v"(b1.y));
      asm("v_add_f32 %0, abs(%1), %0" : "+v"(s2) : "v"(c0.x));
      asm("v_add_f32 %0, abs(%1), %0" : "+v"(s2) : "v"(c0.y));
      asm("v_add_f32 %0, abs(%1), %0" : "+v"(s2) : "v"(c1.x));
      asm("v_add_f32 %0, abs(%1), %0" : "+v"(s2) : "v"(c1.y));
      asm("v_add_f32 %0, abs(%1), %0" : "+v"(s3) : "v"(e0.x));
      asm("v_add_f32 %0, abs(%1), %0" : "+v"(s3) : "v"(e0.y));
      asm("v_add_f32 %0, abs(%1), %0" : "+v"(s3) : "v"(e1.x));
      asm("v_add_f32 %0, abs(%1), %0" : "+v"(s3) : "v"(e1.y));
    }
    best = fminf(best, (s0 + s1) + (s2 + s3));
  }
  mindP[((size_t)jz * BH + row) * LLOC + kk] = best;
}

// ---------------------------------------------------------------------------
// exact rank selection over folded min of the 4 partials
__global__ __launch_bounds__(256) void k_select(const float* __restrict__ mindP,
                                                int* __restrict__ sel) {
  int row = blockIdx.y;
  int i = blockIdx.x * 256 + threadIdx.x;
  __shared__ float dd[LLOC];
  const size_t stride = (size_t)BH * LLOC;
  for (int e = threadIdx.x; e < LLOC; e += 256) {
    size_t o = (size_t)row * LLOC + e;
    float m0 = fminf(mindP[o], mindP[o + stride]);
    float m1 = fminf(mindP[o + 2 * stride], mindP[o + 3 * stride]);
    dd[e] = fminf(m0, m1);
  }
  __syncthreads();
  float di = dd[i];
  int rank = 0;
  for (int j = 0; j < LLOC; j += 4) {
    float4 dj = *(const float4*)&dd[j];
    rank += (dj.x < di) || (dj.x == di && (j+0) < i);
    rank += (dj.y < di) || (dj.y == di && (j+1) < i);
    rank += (dj.z < di) || (dj.z == di && (j+2) < i);
    rank += (dj.w < di) || (dj.w == di && (j+3) < i);
  }
  if (rank < TKSEL) sel[row * TKSEL + rank] = i;
}

// ---------------------------------------------------------------------------
// gather selected K (f32 -> swizzled bf16 [row][288][64]) and V transposed
// (bf16 [row][64][288]) for MFMA attention
__global__ __launch_bounds__(256) void k_gather(const float* __restrict__ K,
    const unsigned short* __restrict__ Vb, const int* __restrict__ sel,
    unsigned short* __restrict__ Kc, unsigned short* __restrict__ Vt) {
  int row = blockIdx.x;
  int d = threadIdx.x & 63;
  for (int ki = threadIdx.x >> 6; ki < TKSEL; ki += 4) {
    int k = sel[row * TKSEL + ki];
    float kv = K[((size_t)row * LLOC + k) * 64 + d];
    Kc[((size_t)row * TKSEL + ki) * 64 + (((d >> 3) ^ (ki & 7)) << 3) + (d & 7)] = f2bf(kv);
    Vt[((size_t)row * 64 + d) * TKSEL + ki] = Vb[((size_t)row * LLOC + k) * 64 + d];
  }
}

// ---------------------------------------------------------------------------
// MFMA attention: block=(36 q-tiles of 64, 64 rows), 4 waves x 16 q.
// S^T[k][q]=mfma(K,Q); exp in-reg; P bounced via per-wave LDS; O^T[d][q]=mfma(V^T,P).
// No max-subtraction (s in [-1,1]). Output bf16 AOb[b][loc][h*64+d].
__global__ __launch_bounds__(256) void k_attn_mfma(
    const unsigned short* __restrict__ Qb, const unsigned short* __restrict__ Kc,
    const unsigned short* __restrict__ Vt, unsigned short* __restrict__ AOb) {
  int row = blockIdx.y, q0 = blockIdx.x * 64;
  int t = threadIdx.x, l = t & 63, w = t >> 6;
  int q15 = l & 15, l4 = l >> 4;
  __shared__ unsigned short Qsm[64 * 64];    // swizzled chunks (from Qb)
  __shared__ unsigned short Ksm[96 * 64];    // swizzled chunks (from Kc)
  __shared__ unsigned short Vsm[64 * 120];   // V^T rows padded to 120
  __shared__ unsigned short Psm[4 * 512];    // per-wave 16q x 32k, slot-swizzled

  f32x4 oacc[4];
#pragma unroll
  for (int dt = 0; dt < 4; ++dt) oacc[dt] = (f32x4){0.f, 0.f, 0.f, 0.f};
  float lsum = 0.f;

  // stage Q tile once (global pre-swizzled -> linear copy)
  const char* QbC = (const char*)(Qb + ((size_t)row * LLOC + q0) * 64);
#pragma unroll
  for (int i = 0; i < 2; ++i)
    GLOAD_LDS(QbC + (size_t)(i * 256 + w * 64 + l) * 16, ((char*)Qsm) + (i * 256 + w * 64) * 16);

  for (int c = 0; c < 3; ++c) {
    // stage K chunk (pre-swizzled -> linear)
    const char* KcC = (const char*)(Kc + (((size_t)row * TKSEL) + c * 96) * 64);
#pragma unroll
    for (int i = 0; i < 3; ++i)
      GLOAD_LDS(KcC + (size_t)(i * 256 + w * 64 + l) * 16, ((char*)Ksm) + (i * 256 + w * 64) * 16);
    // stage V^T chunk into padded rows (reg-staged)
#pragma unroll
    for (int i = 0; i < 3; ++i) {
      int s = i * 256 + t;             // 0..767
      int d = s / 12, j = s % 12;
      uint4 v = *(const uint4*)(Vt + ((size_t)row * 64 + d) * TKSEL + c * 96 + j * 8);
      *(uint4*)((char*)Vsm + d * 240 + j * 16) = v;
    }
    __syncthreads();

    // QK^T: S^T[k][q], 6 k-tiles
    f32x4 sacc[6];
#pragma unroll
    for (int kt = 0; kt < 6; ++kt) sacc[kt] = (f32x4){0.f, 0.f, 0.f, 0.f};
#pragma unroll
    for (int ks = 0; ks < 2; ++ks) {
      int qrow = w * 16 + q15;
      short8 qf = *(const short8*)(Qsm + qrow * 64 + (((ks * 4 + l4) ^ (qrow & 7)) << 3));
#pragma unroll
      for (int kt = 0; kt < 6; ++kt) {
        int krow = kt * 16 + q15;
        short8 kf = *(const short8*)(Ksm + krow * 64 + (((ks * 4 + l4) ^ (krow & 7)) << 3));
        sacc[kt] = __builtin_amdgcn_mfma_f32_16x16x32_bf16(kf, qf, sacc[kt], 0, 0, 0);
      }
    }

    // softmax exp + PV per 32-key sub-chunk
    char* Pw = (char*)(Psm + w * 512);
#pragma unroll
    for (int s3 = 0; s3 < 3; ++s3) {
#pragma unroll
      for (int h2 = 0; h2 < 2; ++h2) {
        int kt = 2 * s3 + h2;
        float p0 = expf(sacc[kt][0]), p1 = expf(sacc[kt][1]);
        float p2 = expf(sacc[kt][2]), p3 = expf(sacc[kt][3]);
        lsum += (p0 + p1) + (p2 + p3);
        unsigned lo = (unsigned)f2bf(p0) | ((unsigned)f2bf(p1) << 16);
        unsigned hi = (unsigned)f2bf(p2) | ((unsigned)f2bf(p3) << 16);
        int sl = (h2 * 4 + l4) ^ ((q15 & 3) << 1);
        *(uint2*)(Pw + q15 * 64 + sl * 8) = make_uint2(lo, hi);
      }
      short8 pB = *(const short8*)(Pw + q15 * 64 + (((2 * l4) ^ ((q15 & 3) << 1)) * 8));
#pragma unroll
      for (int dt = 0; dt < 4; ++dt) {
        short8 vA = *(const short8*)(Vsm + (dt * 16 + q15) * 120 + s3 * 32 + l4 * 8);
        oacc[dt] = __builtin_amdgcn_mfma_f32_16x16x32_bf16(vA, pB, oacc[dt], 0, 0, 0);
      }
    }
    __syncthreads();
  }

  // normalize and write
  lsum += __shfl_xor(lsum, 16, 64);
  lsum += __shfl_xor(lsum, 32, 64);
  float inv = 1.f / lsum;
  int bq = row >> 3, hq = row & 7;
  int loc = q0 + w * 16 + q15;
  unsigned short* op = AOb + ((size_t)bq * LLOC + loc) * 512 + hq * 64;
#pragma unroll
  for (int dt = 0; dt < 4; ++dt) {
    unsigned w0 = (unsigned)f2bf(oacc[dt][0] * inv) | ((unsigned)f2bf(oacc[dt][1] * inv) << 16);
    unsigned w1 = (unsigned)f2bf(oacc[dt][2] * inv) | ((unsigned)f2bf(oacc[dt][3] * inv) << 16);
    *(uint2*)(op + dt * 16 + l4 * 4) = make_uint2(w0, w1);
  }
}

// ---------------------------------------------------------------------------
// FUSED final: channel-LN stats over CO + out = gamma*LN(CO)*g + qsrc.
__global__ __launch_bounds__(256) void k_final_f(const float* __restrict__ CO,
    const float* __restrict__ g, const float* __restrict__ gamma,
    const float* __restrict__ qsrc, float* __restrict__ out) {
  int b = blockIdx.y, loc0 = blockIdx.x * 64;
  int t = threadIdx.x, lx = t & 63, cg = t >> 6;
  const float* cb = CO + (size_t)b * CC * LLOC;
  float s = 0.f, s2 = 0.f;
  for (int c = cg; c < CC; c += 4) {
    float v = cb[(size_t)c * LLOC + loc0 + lx];
    s += v; s2 += v * v;
  }
  __shared__ float sh[2][256];
  __shared__ float mS[64], rS[64];
  sh[0][t] = s; sh[1][t] = s2;
  __syncthreads();
  if (t < 64) {
    float S  = sh[0][t] + sh[0][t+64] + sh[0][t+128] + sh[0][t+192];
    float S2 = sh[1][t] + sh[1][t+64] + sh[1][t+128] + sh[1][t+192];
    float mean = S * (1.f/512.f);
    float var  = S2 * (1.f/512.f) - mean * mean;
    mS[t] = mean;
    rS[t] = 1.f / sqrtf(var + 1e-5f);
  }
  __syncthreads();
  float mean = mS[lx], rstd = rS[lx];
  float ga = gamma[0];
  size_t bbase = (size_t)b * CC * LLOC;
  for (int c = cg; c < CC; c += 4) {
    size_t off = (size_t)c * LLOC + loc0 + lx;
    float v = cb[off];
    out[bbase + off] = ga * (v - mean) * rstd * g[c] + qsrc[bbase + off];
  }
}

// ---------------------------------------------------------------------------
extern "C" void kernel_launch(void* const* d_in, const int* in_sizes, int n_in,
                              void* d_out, int out_size, void* d_ws, size_t ws_size,
                              hipStream_t stream) {
  const float* qsrc  = (const float*)d_in[0];
  const float* ctx   = (const float*)d_in[1];
  const float* g_ctx = (const float*)d_in[2];
  const float* g_qs  = (const float*)d_in[3];
  const float* g_out = (const float*)d_in[4];
  const float* w_kv  = (const float*)d_in[5];
  const float* w_q   = (const float*)d_in[6];
  const float* w_out = (const float*)d_in[7];
  const float* gamma = (const float*)d_in[8];
  float* out = (float*)d_out;

  // workspace layout; total ~171 MiB
  float* ws = (float*)d_ws;
  int*   idxRand  = (int*)(ws + 73728);      // 18432
  int*   sel      = (int*)(ws + 92160);      // 18432
  float* Q  = ws + 258048;                   // 9437184 f
  float* K  = Q + 9437184;                   // 9437184 f
  unsigned short* usb = (unsigned short*)(K + 9437184);
  unsigned short* Vb     = usb;              // 9437184 us
  unsigned short* Xt_hi  = Vb + 9437184;     // 9437184 us (later: AOb)
  unsigned short* Xt_lo  = Xt_hi + 9437184;  // 9437184 us
  unsigned short* Wkv_hi = Xt_lo + 9437184;  // 524288 us
  unsigned short* Wkv_lo = Wkv_hi + 524288;  // 524288 us
  unsigned short* Wq_hi  = Wkv_lo + 524288;  // 262144 us
  unsigned short* Wq_lo  = Wq_hi + 262144;   // 262144 us
  unsigned short* Wo_hi  = Wq_lo + 262144;   // 262144 us
  unsigned short* Wo_lo  = Wo_hi + 262144;   // 262144 us
  float* mindP = (float*)(Wo_lo + 262144);   // 4*64*2304 = 589824 f
  unsigned short* Kc = (unsigned short*)(mindP + 589824);  // 1179648 us
  unsigned short* Vt = Kc + 1179648;                       // 1179648 us
  unsigned short* Qb = Vt + 1179648;                       // 9437184 us
  float* CO = Q;                             // Q dead after attention

  k_threefry<<<72, 256, 0, stream>>>(idxRand);
  k_prep_w_all<<<2048, 256, 0, stream>>>(w_kv, w_q, w_out, g_ctx, g_qs,
                                         Wkv_hi, Wkv_lo, Wq_hi, Wq_lo, Wo_hi, Wo_lo);
  k_prep_xf<<<dim3(36, 8), 256, 0, stream>>>(ctx, Xt_hi, Xt_lo);
  k_mfma3<<<dim3(18, 4, 8), 256, 0, stream>>>(Wkv_hi, Wkv_lo, Xt_hi, Xt_lo, K, nullptr);
  k_mfma1<<<dim3(18, 4, 8), 256, 0, stream>>>(3, Wkv_hi + 512*512, Xt_hi, nullptr, Vb);
  k_prep_xf<<<dim3(36, 8), 256, 0, stream>>>(qsrc, Xt_hi, Xt_lo);
  k_mfma3<<<dim3(18, 4, 8), 256, 0, stream>>>(Wq_hi, Wq_lo, Xt_hi, Xt_lo, Q, Qb);
  k_mindist<<<dim3(9, 64, 4), 256, 0, stream>>>(K, Q, idxRand, mindP);
  k_select<<<dim3(9, 64), 256, 0, stream>>>(mindP, sel);
  k_gather<<<64, 256, 0, stream>>>(K, Vb, sel, Kc, Vt);
  k_attn_mfma<<<dim3(36, 64), 256, 0, stream>>>(Qb, Kc, Vt, Xt_hi);  // AOb = Xt_hi
  k_mfma1<<<dim3(18, 4, 8), 256, 0, stream>>>(2, Wo_hi, Xt_hi, CO, nullptr);
  k_final_f<<<dim3(36, 8), 256, 0, stream>>>(CO, g_out, gamma, qsrc, out);
}

// Round 19
// 637.158 us; speedup vs baseline: 1.0162x; 1.0041x over previous
//
#include <hip/hip_runtime.h>
#include <hip/hip_bf16.h>

// Problem constants
#define BB 8
#define CC 512
#define LLOC 2304        // 48*48
#define NHEADS 8
#define DH 64
#define BH 64            // BB*NHEADS
#define TKSEL 288        // 2304/8

typedef unsigned int u32;
typedef short short8 __attribute__((ext_vector_type(8)));
typedef float f32x4 __attribute__((ext_vector_type(4)));
typedef float f32x2 __attribute__((ext_vector_type(2)));
typedef float f32x16 __attribute__((ext_vector_type(16)));

__device__ inline unsigned short f2bf(float f) {
  unsigned u = __float_as_uint(f);
  u += 0x7FFFu + ((u >> 16) & 1u);
  return (unsigned short)(u >> 16);
}
__device__ inline float b2f(unsigned short h) {
  return __uint_as_float(((unsigned)h) << 16);
}

// global -> LDS direct async copy, 16B/lane; dst = wave-uniform base (+lane*16 implicit)
#define GLOAD_LDS(gsrc, ldst) \
  __builtin_amdgcn_global_load_lds((const __attribute__((address_space(1))) u32*)(gsrc), \
                                   (__attribute__((address_space(3))) u32*)(ldst), 16, 0, 0)

// ---------------------------------------------------------------------------
__device__ inline void tf2x32(unsigned ks0, unsigned ks1, unsigned x0, unsigned x1,
                              unsigned& y0, unsigned& y1) {
  unsigned ks2 = ks0 ^ ks1 ^ 0x1BD11BDAu;
#define TF_R(r) { x0 += x1; x1 = (x1 << (r)) | (x1 >> (32-(r))); x1 ^= x0; }
  x0 += ks0; x1 += ks1;
  TF_R(13) TF_R(15) TF_R(26) TF_R(6)
  x0 += ks1; x1 += ks2 + 1u;
  TF_R(17) TF_R(29) TF_R(16) TF_R(24)
  x0 += ks2; x1 += ks0 + 2u;
  TF_R(13) TF_R(15) TF_R(26) TF_R(6)
  x0 += ks0; x1 += ks1 + 3u;
  TF_R(17) TF_R(29) TF_R(16) TF_R(24)
  x0 += ks1; x1 += ks2 + 4u;
  TF_R(13) TF_R(15) TF_R(26) TF_R(6)
  x0 += ks2; x1 += ks0 + 5u;
#undef TF_R
  y0 = x0; y1 = x1;
}

// JAX randint(key(42), (64,288), 0, 2304), partitionable threefry, XOR-fold
__global__ __launch_bounds__(256) void k_threefry(int* __restrict__ idxRand) {
  unsigned i = blockIdx.x * 256 + threadIdx.x;   // 0..18431
  if (i >= 18432u) return;
  unsigned a0, a1, b0, b1;
  tf2x32(0u, 42u, 0u, 0u, a0, a1);   // k1
  tf2x32(0u, 42u, 0u, 1u, b0, b1);   // k2
  unsigned h0, h1, l0, l1;
  tf2x32(a0, a1, 0u, i, h0, h1);
  tf2x32(b0, b1, 0u, i, l0, l1);
  unsigned h = h0 ^ h1;
  unsigned l = l0 ^ l1;
  const unsigned span = 2304u;
  idxRand[i] = (int)(((h % span) * 256u + (l % span)) % span);
}

// ---------------------------------------------------------------------------
// All three W -> bf16 hi/lo conversions in one launch (range dispatch).
__global__ __launch_bounds__(256) void k_prep_w_all(
    const float* __restrict__ w_kv, const float* __restrict__ w_q,
    const float* __restrict__ w_out, const float* __restrict__ g_ctx,
    const float* __restrict__ g_qs,
    unsigned short* __restrict__ Wkv_hi, unsigned short* __restrict__ Wkv_lo,
    unsigned short* __restrict__ Wq_hi,  unsigned short* __restrict__ Wq_lo,
    unsigned short* __restrict__ Wo_hi,  unsigned short* __restrict__ Wo_lo) {
  int i2 = (blockIdx.x * 256 + threadIdx.x) * 2;
  const float* W; const float* G;
  unsigned short *Wh, *Wl; int base;
  if (i2 < 524288) { W = w_kv; G = g_ctx; Wh = Wkv_hi; Wl = Wkv_lo; base = 0; }
  else if (i2 < 786432) { W = w_q; G = g_qs; Wh = Wq_hi; Wl = Wq_lo; base = 524288; }
  else { W = w_out; G = nullptr; Wh = Wo_hi; Wl = Wo_lo; base = 786432; }
  int i = i2 - base;
  int c = i & 511;
  float2 w2 = *(const float2*)&W[i];
  float g0 = G ? G[c] : 1.f, g1 = G ? G[c + 1] : 1.f;
  float f0 = w2.x * g0, f1 = w2.y * g1;
  unsigned short h0 = f2bf(f0), h1 = f2bf(f1);
  unsigned short q0 = f2bf(f0 - b2f(h0)), q1 = f2bf(f1 - b2f(h1));
  *(unsigned*)&Wh[i] = (unsigned)h0 | ((unsigned)h1 << 16);
  *(unsigned*)&Wl[i] = (unsigned)q0 | ((unsigned)q1 << 16);
}

// ---------------------------------------------------------------------------
// FUSED channel-LN stats + normalize + transpose + bf16 hi/lo split:
// X[b][c][loc] -> Xt[b][loc][512]. One block = 64 locs x all 512 c.
__global__ __launch_bounds__(256) void k_prep_xf(const float* __restrict__ X,
    unsigned short* __restrict__ Xh, unsigned short* __restrict__ Xl) {
  int b = blockIdx.y, loc0 = blockIdx.x * 64;
  int t = threadIdx.x, lx = t & 63, cg = t >> 6;
  const float* xb = X + (size_t)b * CC * LLOC;
  float s = 0.f, s2 = 0.f;
  for (int c = cg; c < CC; c += 4) {
    float v = xb[(size_t)c * LLOC + loc0 + lx];
    s += v; s2 += v * v;
  }
  __shared__ float sh[2][256];
  __shared__ float mS[64], rS[64];
  sh[0][t] = s; sh[1][t] = s2;
  __syncthreads();
  if (t < 64) {
    float S  = sh[0][t] + sh[0][t+64] + sh[0][t+128] + sh[0][t+192];
    float S2 = sh[1][t] + sh[1][t+64] + sh[1][t+128] + sh[1][t+192];
    float mean = S * (1.f/512.f);
    float var  = S2 * (1.f/512.f) - mean * mean;
    mS[t] = mean;
    rS[t] = 1.f / sqrtf(var + 1e-5f);
  }
  __syncthreads();
  __shared__ float sm[64][65];
  float mean = mS[lx], rstd = rS[lx];
  int loc = t >> 2, cs = (t & 3) * 16;
  for (int cc = 0; cc < 8; ++cc) {
    int c0 = cc * 64;
#pragma unroll
    for (int i = 0; i < 16; ++i) {
      int c = cg + i * 4;
      float v = xb[(size_t)(c0 + c) * LLOC + loc0 + lx];
      sm[c][lx] = (v - mean) * rstd;
    }
    __syncthreads();
    unsigned uh[8], ul[8];
#pragma unroll
    for (int j = 0; j < 8; ++j) {
      float f0 = sm[cs + j*2][loc];
      float f1 = sm[cs + j*2 + 1][loc];
      unsigned short h0 = f2bf(f0), h1 = f2bf(f1);
      unsigned short q0 = f2bf(f0 - b2f(h0)), q1 = f2bf(f1 - b2f(h1));
      uh[j] = (unsigned)h0 | ((unsigned)h1 << 16);
      ul[j] = (unsigned)q0 | ((unsigned)q1 << 16);
    }
    size_t base = ((size_t)b * LLOC + loc0 + loc) * 512 + c0 + cs;
    *(uint4*)(Xh + base)     = make_uint4(uh[0], uh[1], uh[2], uh[3]);
    *(uint4*)(Xh + base + 8) = make_uint4(uh[4], uh[5], uh[6], uh[7]);
    *(uint4*)(Xl + base)     = make_uint4(ul[0], ul[1], ul[2], ul[3]);
    *(uint4*)(Xl + base + 8) = make_uint4(ul[4], ul[5], ul[6], ul[7]);
    __syncthreads();
  }
}

// ---------------------------------------------------------------------------
// 3-pass split-bf16 MFMA GEMM (~f32 precision) with FUSED L2-NORM epilogue:
// dst = l2norm(W*X^T) over each 64-dim head; K/Q layout out.
// If Qb != nullptr, also emit swizzled bf16 copy (for MFMA attention).
__global__ __launch_bounds__(256) void k_mfma3(
    const unsigned short* __restrict__ Wh, const unsigned short* __restrict__ Wl,
    const unsigned short* __restrict__ Xh, const unsigned short* __restrict__ Xl,
    float* __restrict__ dst, unsigned short* __restrict__ Qb) {
  int b = blockIdx.z;
  int o0 = blockIdx.y * 128, loc0 = blockIdx.x * 128;
  int t = threadIdx.x, l = t & 63, w = t >> 6;
  int wr = w >> 1, wc = w & 1;
  __shared__ unsigned short Ah[128*64], Al[128*64], Bh[128*64], Bl[128*64];
  f32x4 acc[4][4];
#pragma unroll
  for (int i = 0; i < 4; ++i)
#pragma unroll
    for (int j = 0; j < 4; ++j) acc[i][j] = (f32x4){0.f, 0.f, 0.f, 0.f};

  const char* WhC = (const char*)Wh;
  const char* WlC = (const char*)Wl;
  const char* XhC = (const char*)(Xh + (size_t)b * LLOC * 512);
  const char* XlC = (const char*)(Xl + (size_t)b * LLOC * 512);
  int srow = l >> 3;
  int schunk = (l & 7) ^ srow;

  for (int kt = 0; kt < 8; ++kt) {
    int kb = kt * 128;
#pragma unroll
    for (int j = 0; j < 4; ++j) {
      int r = w * 32 + j * 8;
      size_t arow = (size_t)(o0 + r + srow) * 1024 + kb + schunk * 16;
      size_t brow = (size_t)(loc0 + r + srow) * 1024 + kb + schunk * 16;
      GLOAD_LDS(WhC + arow, ((char*)Ah) + r * 128);
      GLOAD_LDS(WlC + arow, ((char*)Al) + r * 128);
      GLOAD_LDS(XhC + brow, ((char*)Bh) + r * 128);
      GLOAD_LDS(XlC + brow, ((char*)Bl) + r * 128);
    }
    __syncthreads();
#pragma unroll
    for (int ks = 0; ks < 2; ++ks) {
      short8 ah[4], al[4], bh[4], bl[4];
#pragma unroll
      for (int ot = 0; ot < 4; ++ot) {
        int row = wr * 64 + ot * 16 + (l & 15);
        int off = row * 128 + ((ks * 4 + (l >> 4)) ^ (row & 7)) * 16;
        ah[ot] = *(const short8*)(((const char*)Ah) + off);
        al[ot] = *(const short8*)(((const char*)Al) + off);
      }
#pragma unroll
      for (int bt = 0; bt < 4; ++bt) {
        int row = wc * 64 + bt * 16 + (l & 15);
        int off = row * 128 + ((ks * 4 + (l >> 4)) ^ (row & 7)) * 16;
        bh[bt] = *(const short8*)(((const char*)Bh) + off);
        bl[bt] = *(const short8*)(((const char*)Bl) + off);
      }
#pragma unroll
      for (int ot = 0; ot < 4; ++ot)
#pragma unroll
        for (int bt = 0; bt < 4; ++bt) {
          acc[ot][bt] = __builtin_amdgcn_mfma_f32_16x16x32_bf16(ah[ot], bh[bt], acc[ot][bt], 0, 0, 0);
          acc[ot][bt] = __builtin_amdgcn_mfma_f32_16x16x32_bf16(ah[ot], bl[bt], acc[ot][bt], 0, 0, 0);
          acc[ot][bt] = __builtin_amdgcn_mfma_f32_16x16x32_bf16(al[ot], bh[bt], acc[ot][bt], 0, 0, 0);
        }
    }
    __syncthreads();
  }
  // fused L2-norm epilogue: each wave's wr half = one 64-dim head
  int head = (o0 >> 6) + wr;
#pragma unroll
  for (int bt = 0; bt < 4; ++bt) {
    float ss = 0.f;
#pragma unroll
    for (int ot = 0; ot < 4; ++ot)
#pragma unroll
      for (int r = 0; r < 4; ++r) ss += acc[ot][bt][r] * acc[ot][bt][r];
    ss += __shfl_xor(ss, 16, 64);
    ss += __shfl_xor(ss, 32, 64);
    float sc = 1.f / fmaxf(sqrtf(ss), 1e-12f);
    int loc = loc0 + wc * 64 + bt * 16 + (l & 15);
    size_t vecbase = (((size_t)(b * NHEADS + head)) * LLOC + loc) * DH;
#pragma unroll
    for (int ot = 0; ot < 4; ++ot)
#pragma unroll
      for (int r = 0; r < 4; ++r) {
        int d = ot * 16 + (l >> 4) * 4 + r;
        float v = acc[ot][bt][r] * sc;
        dst[vecbase + d] = v;
        if (Qb) Qb[vecbase + ((((d >> 3) ^ (loc & 7)) << 3) | (d & 7))] = f2bf(v);
      }
  }
}

// ---------------------------------------------------------------------------
// single-pass bf16 MFMA GEMM.  mode 3: -> V bf16 [bh][loc][64]
//                              mode 2: -> CO f32 [b][c][loc]
__global__ __launch_bounds__(256) void k_mfma1(int mode,
    const unsigned short* __restrict__ W, const unsigned short* __restrict__ X,
    float* __restrict__ outF, unsigned short* __restrict__ outU) {
  int b = blockIdx.z;
  int o0 = blockIdx.y * 128, loc0 = blockIdx.x * 128;
  int t = threadIdx.x, l = t & 63, w = t >> 6;
  int wr = w >> 1, wc = w & 1;
  __shared__ unsigned short Asm[128*64], Bsm[128*64];
  f32x4 acc[4][4];
#pragma unroll
  for (int i = 0; i < 4; ++i)
#pragma unroll
    for (int j = 0; j < 4; ++j) acc[i][j] = (f32x4){0.f, 0.f, 0.f, 0.f};
  const char* Wc = (const char*)W;
  const char* Xc = (const char*)(X + (size_t)b * LLOC * 512);
  int srow = l >> 3;
  int schunk = (l & 7) ^ srow;
  for (int kt = 0; kt < 8; ++kt) {
    int kb = kt * 128;
#pragma unroll
    for (int j = 0; j < 4; ++j) {
      int r = w * 32 + j * 8;
      GLOAD_LDS(Wc + (size_t)(o0 + r + srow) * 1024 + kb + schunk * 16,
                ((char*)Asm) + r * 128);
      GLOAD_LDS(Xc + (size_t)(loc0 + r + srow) * 1024 + kb + schunk * 16,
                ((char*)Bsm) + r * 128);
    }
    __syncthreads();
#pragma unroll
    for (int ks = 0; ks < 2; ++ks) {
      short8 af[4], bf[4];
#pragma unroll
      for (int ot = 0; ot < 4; ++ot) {
        int row = wr * 64 + ot * 16 + (l & 15);
        af[ot] = *(const short8*)(((const char*)Asm) + row * 128 + (((ks*4 + (l>>4)) ^ (row&7)) * 16));
      }
#pragma unroll
      for (int bt = 0; bt < 4; ++bt) {
        int row = wc * 64 + bt * 16 + (l & 15);
        bf[bt] = *(const short8*)(((const char*)Bsm) + row * 128 + (((ks*4 + (l>>4)) ^ (row&7)) * 16));
      }
#pragma unroll
      for (int ot = 0; ot < 4; ++ot)
#pragma unroll
        for (int bt = 0; bt < 4; ++bt)
          acc[ot][bt] = __builtin_amdgcn_mfma_f32_16x16x32_bf16(af[ot], bf[bt], acc[ot][bt], 0, 0, 0);
    }
    __syncthreads();
  }
#pragma unroll
  for (int ot = 0; ot < 4; ++ot) {
    int ob = o0 + wr * 64 + ot * 16 + (l >> 4) * 4;
#pragma unroll
    for (int bt = 0; bt < 4; ++bt) {
      int loc = loc0 + wc * 64 + bt * 16 + (l & 15);
#pragma unroll
      for (int r = 0; r < 4; ++r) {
        int o = ob + r;
        float v = acc[ot][bt][r];
        if (mode == 2)
          outF[((size_t)b * CC + o) * LLOC + loc] = v;
        else
          outU[(((size_t)(b * NHEADS + (o >> 6))) * LLOC + loc) * DH + (o & 63)] = f2bf(v);
      }
    }
  }
}

// ---------------------------------------------------------------------------
// partial min L1 distance, ZERO-LDS inner loop: queries are wave-uniform, so
// they are fetched via SMEM (4x s_load_dwordx16 -> 64 SGPRs per j) and fed to
// v_pk_add_f32 as SGPR-pair operands. Keys: 32 f32x2 pinned in VGPRs.
// grid (9 key-chunks of 256, 64 rows, 4 q-chunks of 72), block 256
__global__ __launch_bounds__(256) void k_mindist(const float* __restrict__ K,
    const float* __restrict__ Q, const int* __restrict__ idxRand,
    float* __restrict__ mindP) {
  int chunk = blockIdx.x, row = blockIdx.y, jz = blockIdx.z;
  int t = threadIdx.x;
  int kk = chunk * 256 + t;
  f32x2 kv[32];
  const f32x2* kp = (const f32x2*)&K[((size_t)row * LLOC + kk) * 64];
#pragma unroll
  for (int d = 0; d < 32; ++d) kv[d] = kp[d];
#pragma unroll
  for (int d = 0; d < 32; ++d) asm volatile("" : "+v"(kv[d]));
  const int* idx = idxRand + row * TKSEL + jz * 72;
  const float* Qrow = Q + (size_t)row * LLOC * 64;
  float best = 3.402823e38f;
  for (int j = 0; j < 72; ++j) {
    unsigned long long addr = (unsigned long long)(Qrow + (size_t)idx[j] * 64);
    f32x16 qA, qB, qC, qD;
    asm volatile("s_load_dwordx16 %0, %4, 0x0\n\t"
                 "s_load_dwordx16 %1, %4, 0x40\n\t"
                 "s_load_dwordx16 %2, %4, 0x80\n\t"
                 "s_load_dwordx16 %3, %4, 0xc0"
                 : "=s"(qA), "=s"(qB), "=s"(qC), "=s"(qD) : "s"(addr));
    asm volatile("s_waitcnt lgkmcnt(0)" : "+s"(qA), "+s"(qB), "+s"(qC), "+s"(qD));
    float s0 = 0.f, s1 = 0.f, s2 = 0.f, s3 = 0.f;
#define DSTEP(D) { \
      f32x2 qa0 = __builtin_shufflevector(qA, qA, 4*(D) + 0, 4*(D) + 1); \
      f32x2 qa1 = __builtin_shufflevector(qA, qA, 4*(D) + 2, 4*(D) + 3); \
      f32x2 qb0 = __builtin_shufflevector(qB, qB, 4*(D) + 0, 4*(D) + 1); \
      f32x2 qb1 = __builtin_shufflevector(qB, qB, 4*(D) + 2, 4*(D) + 3); \
      f32x2 qc0 = __builtin_shufflevector(qC, qC, 4*(D) + 0, 4*(D) + 1); \
      f32x2 qc1 = __builtin_shufflevector(qC, qC, 4*(D) + 2, 4*(D) + 3); \
      f32x2 qd0 = __builtin_shufflevector(qD, qD, 4*(D) + 0, 4*(D) + 1); \
      f32x2 qd1 = __builtin_shufflevector(qD, qD, 4*(D) + 2, 4*(D) + 3); \
      f32x2 a0, a1, b0, b1, c0, c1, e0, e1; \
      asm("v_pk_add_f32 %0, %1, %2 neg_lo:[0,1] neg_hi:[0,1]" : "=v"(a0) : "v"(kv[2*(D)]),         "s"(qa0)); \
      asm("v_pk_add_f32 %0, %1, %2 neg_lo:[0,1] neg_hi:[0,1]" : "=v"(a1) : "v"(kv[2*(D) + 1]),     "s"(qa1)); \
      asm("v_pk_add_f32 %0, %1, %2 neg_lo:[0,1] neg_hi:[0,1]" : "=v"(b0) : "v"(kv[8 + 2*(D)]),     "s"(qb0)); \
      asm("v_pk_add_f32 %0, %1, %2 neg_lo:[0,1] neg_hi:[0,1]" : "=v"(b1) : "v"(kv[8 + 2*(D) + 1]), "s"(qb1)); \
      asm("v_pk_add_f32 %0, %1, %2 neg_lo:[0,1] neg_hi:[0,1]" : "=v"(c0) : "v"(kv[16 + 2*(D)]),    "s"(qc0)); \
      asm("v_pk_add_f32 %0, %1, %2 neg_lo:[0,1] neg_hi:[0,1]" : "=v"(c1) : "v"(kv[16 + 2*(D) + 1]),"s"(qc1)); \
      asm("v_pk_add_f32 %0, %1, %2 neg_lo:[0,1] neg_hi:[0,1]" : "=v"(e0) : "v"(kv[24 + 2*(D)]),    "s"(qd0)); \
      asm("v_pk_add_f32 %0, %1, %2 neg_lo:[0,1] neg_hi:[0,1]" : "=v"(e1) : "v"(kv[24 + 2*(D) + 1]),"s"(qd1)); \
      asm("v_add_f32 %0, abs(%1), %0" : "+v"(s0) : "v"(a0.x)); \
      asm("v_add_f32 %0, abs(%1), %0" : "+v"(s0) : "v"(a0.y)); \
      asm("v_add_f32 %0, abs(%1), %0" : "+v"(s0) : "v"(a1.x)); \
      asm("v_add_f32 %0, abs(%1), %0" : "+v"(s0) : "v"(a1.y)); \
      asm("v_add_f32 %0, abs(%1), %0" : "+v"(s1) : "v"(b0.x)); \
      asm("v_add_f32 %0, abs(%1), %0" : "+v"(s1) : "v"(b0.y)); \
      asm("v_add_f32 %0, abs(%1), %0" : "+v"(s1) : "v"(b1.x)); \
      asm("v_add_f32 %0, abs(%1), %0" : "+v"(s1) : "v"(b1.y)); \
      asm("v_add_f32 %0, abs(%1), %0" : "+v"(s2) : "v"(c0.x)); \
      asm("v_add_f32 %0, abs(%1), %0" : "+v"(s2) : "v"(c0.y)); \
      asm("v_add_f32 %0, abs(%1), %0" : "+v"(s2) : "v"(c1.x)); \
      asm("v_add_f32 %0, abs(%1), %0" : "+v"(s2) : "v"(c1.y)); \
      asm("v_add_f32 %0, abs(%1), %0" : "+v"(s3) : "v"(e0.x)); \
      asm("v_add_f32 %0, abs(%1), %0" : "+v"(s3) : "v"(e0.y)); \
      asm("v_add_f32 %0, abs(%1), %0" : "+v"(s3) : "v"(e1.x)); \
      asm("v_add_f32 %0, abs(%1), %0" : "+v"(s3) : "v"(e1.y)); \
    }
    DSTEP(0) DSTEP(1) DSTEP(2) DSTEP(3)
#undef DSTEP
    best = fminf(best, (s0 + s1) + (s2 + s3));
  }
  mindP[((size_t)jz * BH + row) * LLOC + kk] = best;
}

// ---------------------------------------------------------------------------
// exact rank selection over folded min of the 4 partials
__global__ __launch_bounds__(256) void k_select(const float* __restrict__ mindP,
                                                int* __restrict__ sel) {
  int row = blockIdx.y;
  int i = blockIdx.x * 256 + threadIdx.x;
  __shared__ float dd[LLOC];
  const size_t stride = (size_t)BH * LLOC;
  for (int e = threadIdx.x; e < LLOC; e += 256) {
    size_t o = (size_t)row * LLOC + e;
    float m0 = fminf(mindP[o], mindP[o + stride]);
    float m1 = fminf(mindP[o + 2 * stride], mindP[o + 3 * stride]);
    dd[e] = fminf(m0, m1);
  }
  __syncthreads();
  float di = dd[i];
  int rank = 0;
  for (int j = 0; j < LLOC; j += 4) {
    float4 dj = *(const float4*)&dd[j];
    rank += (dj.x < di) || (dj.x == di && (j+0) < i);
    rank += (dj.y < di) || (dj.y == di && (j+1) < i);
    rank += (dj.z < di) || (dj.z == di && (j+2) < i);
    rank += (dj.w < di) || (dj.w == di && (j+3) < i);
  }
  if (rank < TKSEL) sel[row * TKSEL + rank] = i;
}

// ---------------------------------------------------------------------------
// gather selected K (f32 -> swizzled bf16 [row][288][64]) and V transposed
// (bf16 [row][64][288]) for MFMA attention
__global__ __launch_bounds__(256) void k_gather(const float* __restrict__ K,
    const unsigned short* __restrict__ Vb, const int* __restrict__ sel,
    unsigned short* __restrict__ Kc, unsigned short* __restrict__ Vt) {
  int row = blockIdx.x;
  int d = threadIdx.x & 63;
  for (int ki = threadIdx.x >> 6; ki < TKSEL; ki += 4) {
    int k = sel[row * TKSEL + ki];
    float kv = K[((size_t)row * LLOC + k) * 64 + d];
    Kc[((size_t)row * TKSEL + ki) * 64 + (((d >> 3) ^ (ki & 7)) << 3) + (d & 7)] = f2bf(kv);
    Vt[((size_t)row * 64 + d) * TKSEL + ki] = Vb[((size_t)row * LLOC + k) * 64 + d];
  }
}

// ---------------------------------------------------------------------------
// MFMA attention: block=(36 q-tiles of 64, 64 rows), 4 waves x 16 q.
// S^T[k][q]=mfma(K,Q); exp in-reg; P bounced via per-wave LDS; O^T[d][q]=mfma(V^T,P).
// No max-subtraction (s in [-1,1]). Output bf16 AOb[b][loc][h*64+d].
__global__ __launch_bounds__(256) void k_attn_mfma(
    const unsigned short* __restrict__ Qb, const unsigned short* __restrict__ Kc,
    const unsigned short* __restrict__ Vt, unsigned short* __restrict__ AOb) {
  int row = blockIdx.y, q0 = blockIdx.x * 64;
  int t = threadIdx.x, l = t & 63, w = t >> 6;
  int q15 = l & 15, l4 = l >> 4;
  __shared__ unsigned short Qsm[64 * 64];    // swizzled chunks (from Qb)
  __shared__ unsigned short Ksm[96 * 64];    // swizzled chunks (from Kc)
  __shared__ unsigned short Vsm[64 * 120];   // V^T rows padded to 120
  __shared__ unsigned short Psm[4 * 512];    // per-wave 16q x 32k, slot-swizzled

  f32x4 oacc[4];
#pragma unroll
  for (int dt = 0; dt < 4; ++dt) oacc[dt] = (f32x4){0.f, 0.f, 0.f, 0.f};
  float lsum = 0.f;

  // stage Q tile once (global pre-swizzled -> linear copy)
  const char* QbC = (const char*)(Qb + ((size_t)row * LLOC + q0) * 64);
#pragma unroll
  for (int i = 0; i < 2; ++i)
    GLOAD_LDS(QbC + (size_t)(i * 256 + w * 64 + l) * 16, ((char*)Qsm) + (i * 256 + w * 64) * 16);

  for (int c = 0; c < 3; ++c) {
    // stage K chunk (pre-swizzled -> linear)
    const char* KcC = (const char*)(Kc + (((size_t)row * TKSEL) + c * 96) * 64);
#pragma unroll
    for (int i = 0; i < 3; ++i)
      GLOAD_LDS(KcC + (size_t)(i * 256 + w * 64 + l) * 16, ((char*)Ksm) + (i * 256 + w * 64) * 16);
    // stage V^T chunk into padded rows (reg-staged)
#pragma unroll
    for (int i = 0; i < 3; ++i) {
      int s = i * 256 + t;             // 0..767
      int d = s / 12, j = s % 12;
      uint4 v = *(const uint4*)(Vt + ((size_t)row * 64 + d) * TKSEL + c * 96 + j * 8);
      *(uint4*)((char*)Vsm + d * 240 + j * 16) = v;
    }
    __syncthreads();

    // QK^T: S^T[k][q], 6 k-tiles
    f32x4 sacc[6];
#pragma unroll
    for (int kt = 0; kt < 6; ++kt) sacc[kt] = (f32x4){0.f, 0.f, 0.f, 0.f};
#pragma unroll
    for (int ks = 0; ks < 2; ++ks) {
      int qrow = w * 16 + q15;
      short8 qf = *(const short8*)(Qsm + qrow * 64 + (((ks * 4 + l4) ^ (qrow & 7)) << 3));
#pragma unroll
      for (int kt = 0; kt < 6; ++kt) {
        int krow = kt * 16 + q15;
        short8 kf = *(const short8*)(Ksm + krow * 64 + (((ks * 4 + l4) ^ (krow & 7)) << 3));
        sacc[kt] = __builtin_amdgcn_mfma_f32_16x16x32_bf16(kf, qf, sacc[kt], 0, 0, 0);
      }
    }

    // softmax exp + PV per 32-key sub-chunk
    char* Pw = (char*)(Psm + w * 512);
#pragma unroll
    for (int s3 = 0; s3 < 3; ++s3) {
#pragma unroll
      for (int h2 = 0; h2 < 2; ++h2) {
        int kt = 2 * s3 + h2;
        float p0 = expf(sacc[kt][0]), p1 = expf(sacc[kt][1]);
        float p2 = expf(sacc[kt][2]), p3 = expf(sacc[kt][3]);
        lsum += (p0 + p1) + (p2 + p3);
        unsigned lo = (unsigned)f2bf(p0) | ((unsigned)f2bf(p1) << 16);
        unsigned hi = (unsigned)f2bf(p2) | ((unsigned)f2bf(p3) << 16);
        int sl = (h2 * 4 + l4) ^ ((q15 & 3) << 1);
        *(uint2*)(Pw + q15 * 64 + sl * 8) = make_uint2(lo, hi);
      }
      short8 pB = *(const short8*)(Pw + q15 * 64 + (((2 * l4) ^ ((q15 & 3) << 1)) * 8));
#pragma unroll
      for (int dt = 0; dt < 4; ++dt) {
        short8 vA = *(const short8*)(Vsm + (dt * 16 + q15) * 120 + s3 * 32 + l4 * 8);
        oacc[dt] = __builtin_amdgcn_mfma_f32_16x16x32_bf16(vA, pB, oacc[dt], 0, 0, 0);
      }
    }
    __syncthreads();
  }

  // normalize and write
  lsum += __shfl_xor(lsum, 16, 64);
  lsum += __shfl_xor(lsum, 32, 64);
  float inv = 1.f / lsum;
  int bq = row >> 3, hq = row & 7;
  int loc = q0 + w * 16 + q15;
  unsigned short* op = AOb + ((size_t)bq * LLOC + loc) * 512 + hq * 64;
#pragma unroll
  for (int dt = 0; dt < 4; ++dt) {
    unsigned w0 = (unsigned)f2bf(oacc[dt][0] * inv) | ((unsigned)f2bf(oacc[dt][1] * inv) << 16);
    unsigned w1 = (unsigned)f2bf(oacc[dt][2] * inv) | ((unsigned)f2bf(oacc[dt][3] * inv) << 16);
    *(uint2*)(op + dt * 16 + l4 * 4) = make_uint2(w0, w1);
  }
}

// ---------------------------------------------------------------------------
// FUSED final: channel-LN stats over CO + out = gamma*LN(CO)*g + qsrc.
__global__ __launch_bounds__(256) void k_final_f(const float* __restrict__ CO,
    const float* __restrict__ g, const float* __restrict__ gamma,
    const float* __restrict__ qsrc, float* __restrict__ out) {
  int b = blockIdx.y, loc0 = blockIdx.x * 64;
  int t = threadIdx.x, lx = t & 63, cg = t >> 6;
  const float* cb = CO + (size_t)b * CC * LLOC;
  float s = 0.f, s2 = 0.f;
  for (int c = cg; c < CC; c += 4) {
    float v = cb[(size_t)c * LLOC + loc0 + lx];
    s += v; s2 += v * v;
  }
  __shared__ float sh[2][256];
  __shared__ float mS[64], rS[64];
  sh[0][t] = s; sh[1][t] = s2;
  __syncthreads();
  if (t < 64) {
    float S  = sh[0][t] + sh[0][t+64] + sh[0][t+128] + sh[0][t+192];
    float S2 = sh[1][t] + sh[1][t+64] + sh[1][t+128] + sh[1][t+192];
    float mean = S * (1.f/512.f);
    float var  = S2 * (1.f/512.f) - mean * mean;
    mS[t] = mean;
    rS[t] = 1.f / sqrtf(var + 1e-5f);
  }
  __syncthreads();
  float mean = mS[lx], rstd = rS[lx];
  float ga = gamma[0];
  size_t bbase = (size_t)b * CC * LLOC;
  for (int c = cg; c < CC; c += 4) {
    size_t off = (size_t)c * LLOC + loc0 + lx;
    float v = cb[off];
    out[bbase + off] = ga * (v - mean) * rstd * g[c] + qsrc[bbase + off];
  }
}

// ---------------------------------------------------------------------------
extern "C" void kernel_launch(void* const* d_in, const int* in_sizes, int n_in,
                              void* d_out, int out_size, void* d_ws, size_t ws_size,
                              hipStream_t stream) {
  const float* qsrc  = (const float*)d_in[0];
  const float* ctx   = (const float*)d_in[1];
  const float* g_ctx = (const float*)d_in[2];
  const float* g_qs  = (const float*)d_in[3];
  const float* g_out = (const float*)d_in[4];
  const float* w_kv  = (const float*)d_in[5];
  const float* w_q   = (const float*)d_in[6];
  const float* w_out = (const float*)d_in[7];
  const float* gamma = (const float*)d_in[8];
  float* out = (float*)d_out;

  // workspace layout; total ~171 MiB
  float* ws = (float*)d_ws;
  int*   idxRand  = (int*)(ws + 73728);      // 18432
  int*   sel      = (int*)(ws + 92160);      // 18432
  float* Q  = ws + 258048;                   // 9437184 f
  float* K  = Q + 9437184;                   // 9437184 f
  unsigned short* usb = (unsigned short*)(K + 9437184);
  unsigned short* Vb     = usb;              // 9437184 us
  unsigned short* Xt_hi  = Vb + 9437184;     // 9437184 us (later: AOb)
  unsigned short* Xt_lo  = Xt_hi + 9437184;  // 9437184 us
  unsigned short* Wkv_hi = Xt_lo + 9437184;  // 524288 us
  unsigned short* Wkv_lo = Wkv_hi + 524288;  // 524288 us
  unsigned short* Wq_hi  = Wkv_lo + 524288;  // 262144 us
  unsigned short* Wq_lo  = Wq_hi + 262144;   // 262144 us
  unsigned short* Wo_hi  = Wq_lo + 262144;   // 262144 us
  unsigned short* Wo_lo  = Wo_hi + 262144;   // 262144 us
  float* mindP = (float*)(Wo_lo + 262144);   // 4*64*2304 = 589824 f
  unsigned short* Kc = (unsigned short*)(mindP + 589824);  // 1179648 us
  unsigned short* Vt = Kc + 1179648;                       // 1179648 us
  unsigned short* Qb = Vt + 1179648;                       // 9437184 us
  float* CO = Q;                             // Q dead after attention

  k_threefry<<<72, 256, 0, stream>>>(idxRand);
  k_prep_w_all<<<2048, 256, 0, stream>>>(w_kv, w_q, w_out, g_ctx, g_qs,
                                         Wkv_hi, Wkv_lo, Wq_hi, Wq_lo, Wo_hi, Wo_lo);
  k_prep_xf<<<dim3(36, 8), 256, 0, stream>>>(ctx, Xt_hi, Xt_lo);
  k_mfma3<<<dim3(18, 4, 8), 256, 0, stream>>>(Wkv_hi, Wkv_lo, Xt_hi, Xt_lo, K, nullptr);
  k_mfma1<<<dim3(18, 4, 8), 256, 0, stream>>>(3, Wkv_hi + 512*512, Xt_hi, nullptr, Vb);
  k_prep_xf<<<dim3(36, 8), 256, 0, stream>>>(qsrc, Xt_hi, Xt_lo);
  k_mfma3<<<dim3(18, 4, 8), 256, 0, stream>>>(Wq_hi, Wq_lo, Xt_hi, Xt_lo, Q, Qb);
  k_mindist<<<dim3(9, 64, 4), 256, 0, stream>>>(K, Q, idxRand, mindP);
  k_select<<<dim3(9, 64), 256, 0, stream>>>(mindP, sel);
  k_gather<<<64, 256, 0, stream>>>(K, Vb, sel, Kc, Vt);
  k_attn_mfma<<<dim3(36, 64), 256, 0, stream>>>(Qb, Kc, Vt, Xt_hi);  // AOb = Xt_hi
  k_mfma1<<<dim3(18, 4, 8), 256, 0, stream>>>(2, Wo_hi, Xt_hi, CO, nullptr);
  k_final_f<<<dim3(36, 8), 256, 0, stream>>>(CO, g_out, gamma, qsrc, out);
}